// Round 16
// baseline (585.354 us; speedup 1.0000x reference)
//
#include <hip/hip_runtime.h>

typedef __attribute__((ext_vector_type(8))) short bf8;
typedef __attribute__((ext_vector_type(4))) float f4;

__device__ __forceinline__ ushort f2b(float f) {
  union { float f; unsigned u; } v; v.f = f;
  unsigned u = v.u + 0x7FFFu + ((v.u >> 16) & 1u);
  return (ushort)(u >> 16);
}
__device__ __forceinline__ float b2f(ushort h) {
  union { unsigned u; float f; } v; v.u = ((unsigned)h) << 16; return v.f;
}
__device__ __forceinline__ bf8 pack8(const float* p) {
  f4 a = *(const f4*)p; f4 b = *(const f4*)(p + 4);
  bf8 t;
  t[0] = (short)f2b(a[0]); t[1] = (short)f2b(a[1]);
  t[2] = (short)f2b(a[2]); t[3] = (short)f2b(a[3]);
  t[4] = (short)f2b(b[0]); t[5] = (short)f2b(b[1]);
  t[6] = (short)f2b(b[2]); t[7] = (short)f2b(b[3]);
  return t;
}
__device__ __forceinline__ float sigm(float x) { return 1.f / (1.f + __expf(-x)); }
__device__ __forceinline__ float tanh_f(float x) {
  float a = fabsf(x), e = __expf(-2.f * a);
  return copysignf((1.f - e) / (1.f + e), x);
}

__device__ __forceinline__ void gl16(const void* g, void* l) {
  __builtin_amdgcn_global_load_lds(
      (const __attribute__((address_space(1))) unsigned int*)(uintptr_t)g,
      (__attribute__((address_space(3))) unsigned int*)(uintptr_t)l, 16, 0, 0);
}

#define SFENCE __builtin_amdgcn_sched_barrier(0)
#define RAWBAR { __builtin_amdgcn_s_barrier(); SFENCE; }
#define WAIT_LGKM0 { asm volatile("s_waitcnt lgkmcnt(0)" ::: "memory"); SFENCE; }
#define WAIT_VM(n) { asm volatile("s_waitcnt vmcnt(" #n ")" ::: "memory"); SFENCE; }

// ---------------- f32 -> bf16 convert ----------------
__global__ __launch_bounds__(256) void cvt_k(const float* __restrict__ in,
                                             ushort* __restrict__ out, int n4) {
  int i = blockIdx.x * 256 + threadIdx.x;
  if (i < n4) {
    f4 v = ((const f4*)in)[i];
    ushort4 o;
    o.x = f2b(v[0]); o.y = f2b(v[1]); o.z = f2b(v[2]); o.w = f2b(v[3]);
    ((ushort4*)out)[i] = o;
  }
}

// ---------------- f32 -> bf16 transposing convert: in (R,C) -> out (C,R) ----
__global__ __launch_bounds__(256) void cvtT_k(const float* __restrict__ in,
                                              ushort* __restrict__ out, int R, int C) {
  __shared__ ushort t[64][68];
  const int tid = threadIdx.x;
  const int r0 = blockIdx.x * 64, c0 = blockIdx.y * 64;
  #pragma unroll
  for (int it = 0; it < 4; ++it) {
    int r = (tid >> 4) + 16 * it, c = (tid & 15) * 4;
    f4 v = *(const f4*)(in + (long)(r0 + r) * C + c0 + c);
    #pragma unroll
    for (int j = 0; j < 4; ++j) t[c + j][r] = f2b(v[j]);
  }
  __syncthreads();
  #pragma unroll
  for (int it = 0; it < 4; ++it) {
    int cc = (tid >> 4) + 16 * it, rr = (tid & 15) * 4;
    ushort4 o = { t[cc][rr], t[cc][rr + 1], t[cc][rr + 2], t[cc][rr + 3] };
    *(ushort4*)(out + (long)(c0 + cc) * R + r0 + rr) = o;
  }
}

// ---------------- per-row concat: o[s] = [a[s] | h[s]]  (1024 x 2048) ------
__global__ __launch_bounds__(256) void cat_k(const ushort* __restrict__ a,
                                             const ushort* __restrict__ h,
                                             ushort* __restrict__ o) {
  int i = blockIdx.x * 256 + threadIdx.x;      // 131072
  int s = i >> 7, c8 = (i & 127) << 3;
  *(int4*)(o + (long)s * 2048 + c8) = *(const int4*)(a + (long)s * 1024 + c8);
  *(int4*)(o + (long)s * 2048 + 1024 + c8) = *(const int4*)(h + (long)s * 1024 + c8);
}

// ---------------- tiny weight-fusion kernels ----------------
__global__ void wcombT_k(const float* __restrict__ Wl, const float* __restrict__ W2,
                         ushort* __restrict__ out) {
  int idx = blockIdx.x * 256 + threadIdx.x;  // 8192
  int d = idx >> 7, h = idx & 127;
  float s = 0.f;
  #pragma unroll
  for (int f = 0; f < 64; ++f) s += Wl[d * 64 + f] * W2[h * 64 + f];
  out[d * 128 + h] = f2b(s);
}
__global__ void biasc_k(const float* __restrict__ gb2, const float* __restrict__ Wl,
                        const float* __restrict__ bl, float* __restrict__ bc) {
  int d = threadIdx.x;  // 64
  float s = 0.f;
  #pragma unroll
  for (int f = 0; f < 64; ++f) s += gb2[f] * Wl[d * 64 + f];
  bc[d] = 2.f * s + bl[d];
}
__global__ void wfin_k(const float* __restrict__ Wg2, const float* __restrict__ Wp,
                       float* __restrict__ wf) {
  int idx = threadIdx.x;  // 256
  int d = idx >> 1, c = idx & 1;
  float s = 0.f;
  #pragma unroll
  for (int e = 0; e < 128; ++e) s += Wg2[d * 128 + e] * Wp[c * 128 + e];
  wf[idx] = s;
}

// ====== 256x256-tile bf16 GEMM, BK=32, 64 KiB LDS -> 2 blocks/CU ===========
// Same 2-phase dbuf + counted-vmcnt skeleton as gemm3 (proven), but BK=32:
// per tile 4 gl16 (2A+2B, 16 rows each), 12 ds_read_b128, 32 MFMA,
// vmcnt(4). 16B-chunk swizzle: LDS slot cs holds global chunk cs^((row>>1)&3).
template<int BIASMODE, int RELU>
__global__ __launch_bounds__(512, 2) void gemm4_k(
    const ushort* __restrict__ A, const ushort* __restrict__ B,
    ushort* __restrict__ C, const float* __restrict__ bias, int biasMask,
    int N, int K, int lda, int ldb, int ldc,
    long sAq, long sBq, long sCq)
{
  __shared__ __align__(16) ushort As[2 * 256 * 32];   // 32 KiB
  __shared__ __align__(16) ushort Bs[2 * 256 * 32];   // 32 KiB
  const int tid = threadIdx.x, lane = tid & 63, wv = tid >> 6;
  const int wm = wv >> 2, wn = wv & 3;                // 2M x 4N
  const long bm = (long)blockIdx.x * 256, bn = (long)blockIdx.y * 256;
  const int z = blockIdx.z;
  const ushort* Ap = A + (long)z * sAq + bm * lda;
  const ushort* Bp = B + (long)z * sBq + bn * ldb;
  ushort* Cp = C + (long)z * sCq;
  const int nt = K >> 5;

  // staging rows: gl16#0 -> rows wv*32..+15, gl16#1 -> +16..+31
  const int r0 = wv * 32 + (lane >> 2);
  const int g0 = ((lane & 3) ^ ((r0 >> 1) & 3)) << 3;   // pre-swizzled source chunk
  const ushort* apb0 = Ap + (long)r0 * lda + g0;
  const ushort* apb1 = Ap + (long)(r0 + 16) * lda + g0; // ((r0+16)>>1)&3 == (r0>>1)&3
  const ushort* bpb0 = Bp + (long)r0 * ldb + g0;
  const ushort* bpb1 = Bp + (long)(r0 + 16) * ldb + g0;

  #define STAGE4(T, D) { \
    gl16(apb0 + (T) * 32, &As[(D) * 8192 + (wv * 32) * 32]); \
    gl16(apb1 + (T) * 32, &As[(D) * 8192 + (wv * 32 + 16) * 32]); \
    gl16(bpb0 + (T) * 32, &Bs[(D) * 8192 + (wv * 32) * 32]); \
    gl16(bpb1 + (T) * 32, &Bs[(D) * 8192 + (wv * 32 + 16) * 32]); \
  }

  STAGE4(0, 0);
  if (nt > 1) { STAGE4(1, 1); WAIT_VM(4); }
  else        { WAIT_VM(0); }
  RAWBAR;

  f4 acc[8][4] = {};
  for (int t = 0; t < nt; ++t) {
    const int d = t & 1;
    const ushort* as = As + d * 8192;
    const ushort* bs = Bs + d * 8192;
    bf8 bfr[4], afr[8];
    #pragma unroll
    for (int n = 0; n < 4; ++n) {
      int r = wn * 64 + n * 16 + (lane & 15);
      bfr[n] = *(const bf8*)(bs + r * 32 + (((lane >> 4) ^ ((r >> 1) & 3)) << 3));
    }
    #pragma unroll
    for (int m = 0; m < 8; ++m) {
      int r = wm * 128 + m * 16 + (lane & 15);
      afr[m] = *(const bf8*)(as + r * 32 + (((lane >> 4) ^ ((r >> 1) & 3)) << 3));
    }
    WAIT_LGKM0;          // my frag reads landed in regs
    RAWBAR;              // all waves done reading buf d -> safe to overwrite
    if (t + 2 < nt) STAGE4(t + 2, d);
    __builtin_amdgcn_s_setprio(1);
    #pragma unroll
    for (int m = 0; m < 8; ++m)
      #pragma unroll
      for (int n = 0; n < 4; ++n)
        acc[m][n] = __builtin_amdgcn_mfma_f32_16x16x32_bf16(afr[m], bfr[n], acc[m][n], 0, 0, 0);
    __builtin_amdgcn_s_setprio(0);
    if (t + 1 < nt) {
      if (t + 2 < nt) { WAIT_VM(4); }   // tile t+1 landed; t+2 stays in flight
      else            { WAIT_VM(0); }
      RAWBAR;
    }
  }
  #undef STAGE4

  #pragma unroll
  for (int m = 0; m < 8; ++m) {
    int grow = (int)bm + wm * 128 + m * 16 + ((lane >> 4) << 2);
    #pragma unroll
    for (int n = 0; n < 4; ++n) {
      int col = (int)bn + wn * 64 + n * 16 + (lane & 15);
      #pragma unroll
      for (int rr = 0; rr < 4; ++rr) {
        float v = acc[m][n][rr];
        if (BIASMODE == 1) v += bias[col & biasMask];
        if (BIASMODE == 2) v += bias[(grow + rr) & biasMask];
        if (RELU) v = fmaxf(v, 0.f);
        Cp[(long)(grow + rr) * ldc + col] = f2b(v);
      }
    }
  }
}

// ============ 256x256-tile bf16 MFMA GEMM, 8 waves, dbuf + counted vmcnt ====
// R11-proven body (BK=64). OUTMODE: 0 normal; 3 = fused x-projection.
template<int BIASMODE, int RELU, int OUTMODE>
__global__ __launch_bounds__(512, 2) void gemm3_k(
    const ushort* __restrict__ A, const ushort* __restrict__ B,
    ushort* __restrict__ C, const float* __restrict__ bias, int biasMask,
    int N, int K, int lda, int ldb, int ldc,
    long sAq, long sBq, long sCq,
    const ushort* __restrict__ Wc, const float* __restrict__ bcp)
{
  __shared__ __align__(16) ushort As[2 * 256 * 64];   // 64 KiB
  __shared__ __align__(16) ushort Bs[2 * 256 * 64];   // 64 KiB
  const int tid = threadIdx.x, lane = tid & 63, wv = tid >> 6;
  const int wm = wv >> 2, wn = wv & 3;                // 2M x 4N
  const long bm = (long)blockIdx.x * 256, bn = (long)blockIdx.y * 256;
  const int z = blockIdx.z;
  const ushort* Ap = A + (long)z * sAq + bm * lda;
  const ushort* Bp = B + (long)z * sBq + bn * ldb;
  ushort* Cp = C + (long)z * sCq;
  const int nt = K >> 6;

  const int srow = wv * 32 + (lane >> 3);
  const int scol = ((lane & 7) ^ (srow & 7)) << 3;    // XOR-pre-swizzled source
  const ushort* apb = Ap + (long)srow * lda + scol;
  const ushort* bpb = Bp + (long)srow * ldb + scol;

  #define STAGE3(T, D) { \
    const ushort* ap_ = apb + (T) * 64; \
    const ushort* bp_ = bpb + (T) * 64; \
    ushort* la_ = &As[(D) * 16384 + (wv * 32) * 64]; \
    ushort* lb_ = &Bs[(D) * 16384 + (wv * 32) * 64]; \
    _Pragma("unroll") \
    for (int i_ = 0; i_ < 4; ++i_) gl16(ap_ + (long)(i_ * 8) * lda, la_ + i_ * 512); \
    _Pragma("unroll") \
    for (int i_ = 0; i_ < 4; ++i_) gl16(bp_ + (long)(i_ * 8) * ldb, lb_ + i_ * 512); \
  }

  STAGE3(0, 0);
  if (nt > 1) { STAGE3(1, 1); WAIT_VM(8); }
  else        { WAIT_VM(0); }
  RAWBAR;

  f4 acc[8][4] = {};
  for (int t = 0; t < nt; ++t) {
    const int d = t & 1;
    const ushort* as = As + d * 16384;
    const ushort* bs = Bs + d * 16384;
    // ---- ks = 0 half ----
    bf8 b0[4], a0[8];
    #pragma unroll
    for (int n = 0; n < 4; ++n) {
      int r = wn * 64 + n * 16 + (lane & 15);
      b0[n] = *(const bf8*)(bs + r * 64 + (((lane >> 4) ^ (r & 7)) << 3));
    }
    #pragma unroll
    for (int m = 0; m < 8; ++m) {
      int r = wm * 128 + m * 16 + (lane & 15);
      a0[m] = *(const bf8*)(as + r * 64 + (((lane >> 4) ^ (r & 7)) << 3));
    }
    __builtin_amdgcn_s_setprio(1);
    #pragma unroll
    for (int m = 0; m < 8; ++m)
      #pragma unroll
      for (int n = 0; n < 4; ++n)
        acc[m][n] = __builtin_amdgcn_mfma_f32_16x16x32_bf16(a0[m], b0[n], acc[m][n], 0, 0, 0);
    __builtin_amdgcn_s_setprio(0);
    // ---- ks = 1 half ----
    bf8 b1[4], a1[8];
    #pragma unroll
    for (int n = 0; n < 4; ++n) {
      int r = wn * 64 + n * 16 + (lane & 15);
      b1[n] = *(const bf8*)(bs + r * 64 + (((4 + (lane >> 4)) ^ (r & 7)) << 3));
    }
    #pragma unroll
    for (int m = 0; m < 8; ++m) {
      int r = wm * 128 + m * 16 + (lane & 15);
      a1[m] = *(const bf8*)(as + r * 64 + (((4 + (lane >> 4)) ^ (r & 7)) << 3));
    }
    WAIT_LGKM0;          // all my reads of buf d landed in regs
    RAWBAR;              // every wave done reading buf d -> safe to overwrite
    if (t + 2 < nt) STAGE3(t + 2, d);
    __builtin_amdgcn_s_setprio(1);
    #pragma unroll
    for (int m = 0; m < 8; ++m)
      #pragma unroll
      for (int n = 0; n < 4; ++n)
        acc[m][n] = __builtin_amdgcn_mfma_f32_16x16x32_bf16(a1[m], b1[n], acc[m][n], 0, 0, 0);
    __builtin_amdgcn_s_setprio(0);
    if (t + 1 < nt) {
      if (t + 2 < nt) { WAIT_VM(8); }   // tile t+1 landed; t+2 stays in flight
      else            { WAIT_VM(0); }
      RAWBAR;
    }
  }
  #undef STAGE3

  if (OUTMODE == 3) {
    // --- stage P into LDS [s][h] (swizzled); t_local = wm: t0->As, t1->Bs ---
    ushort* Ps = (wm == 0) ? (ushort*)As : (ushort*)Bs;
    #pragma unroll
    for (int m = 0; m < 8; ++m) {
      int hq = m * 16 + ((lane >> 4) << 2);
      #pragma unroll
      for (int n = 0; n < 4; ++n) {
        int s = wn * 64 + n * 16 + (lane & 15);
        int key = (s & 7) << 4;
        #pragma unroll
        for (int rr = 0; rr < 4; ++rr)
          Ps[s * 128 + ((hq + rr) ^ key)] = f2b(acc[m][n][rr]);
      }
    }
    WAIT_LGKM0;   // drain my ds_writes before the raw barrier
    RAWBAR;
    // --- mini-GEMM: x[s,d] = sum_h P[s][h] * Wc[d][h] + bcp[d] ---
    const int tl = wm, sq = wn;
    const ushort* Pw = (tl == 0) ? (const ushort*)As : (const ushort*)Bs;
    const int sbase = sq * 64;
    f4 xacc[4][4] = {};
    #pragma unroll
    for (int kk = 0; kk < 4; ++kk) {
      bf8 pa[4], wb[4];
      int hq = kk * 32 + ((lane >> 4) << 3);
      #pragma unroll
      for (int mt = 0; mt < 4; ++mt) {
        int s = sbase + mt * 16 + (lane & 15);
        pa[mt] = *(const bf8*)(Pw + s * 128 + (hq ^ ((s & 7) << 4)));
      }
      #pragma unroll
      for (int ntt = 0; ntt < 4; ++ntt) {
        int dd = ntt * 16 + (lane & 15);
        wb[ntt] = *(const bf8*)(Wc + dd * 128 + hq);
      }
      #pragma unroll
      for (int mt = 0; mt < 4; ++mt)
        #pragma unroll
        for (int ntt = 0; ntt < 4; ++ntt)
          xacc[mt][ntt] = __builtin_amdgcn_mfma_f32_16x16x32_bf16(pa[mt], wb[ntt], xacc[mt][ntt], 0, 0, 0);
    }
    const int tg = (int)(bm >> 7) + tl;
    #pragma unroll
    for (int mt = 0; mt < 4; ++mt)
      #pragma unroll
      for (int ntt = 0; ntt < 4; ++ntt) {
        int dd = ntt * 16 + (lane & 15);
        float bb = bcp[dd];
        #pragma unroll
        for (int rr = 0; rr < 4; ++rr) {
          int s = sbase + mt * 16 + ((lane >> 4) << 2) + rr;
          long seq = (long)z * 1024 + bn + s;
          C[((long)tg * 8192 + seq) * 64 + dd] = f2b(xacc[mt][ntt][rr] + bb);
        }
      }
  } else {
    #pragma unroll
    for (int m = 0; m < 8; ++m) {
      int grow = (int)bm + wm * 128 + m * 16 + ((lane >> 4) << 2);
      #pragma unroll
      for (int n = 0; n < 4; ++n) {
        int col = (int)bn + wn * 64 + n * 16 + (lane & 15);
        #pragma unroll
        for (int rr = 0; rr < 4; ++rr) {
          float v = acc[m][n][rr];
          if (BIASMODE == 1) v += bias[col & biasMask];
          if (BIASMODE == 2) v += bias[(grow + rr) & biasMask];
          if (RELU) v = fmaxf(v, 0.f);
          Cp[(long)(grow + rr) * ldc + col] = f2b(v);
        }
      }
    }
  }
}

// ---------------- 128x128 bf16 MFMA GEMM, 2-phase dbuf ----------------------
// BSRC: 0 = B bf16 via global_load_lds; 1 = B f32 reg-staged + converted
// (ONLY valid when nt == 1, e.g. the K=64 XT gemm — counted vmcnt unused).
template<int BIASMODE, int RELU, int OUTMODE, int BSRC>
__global__ __launch_bounds__(256) void gemm2_k(
    const ushort* __restrict__ A, const void* __restrict__ Bv,
    ushort* __restrict__ C, const float* __restrict__ bias, int biasMask,
    int N, int K, int lda, int ldb, int ldc, int ZD,
    long sAq, long sAr, long sBq, long sBr, long sCq, long sCr)
{
  __shared__ __align__(16) ushort As[2 * 128 * 64];
  __shared__ __align__(16) ushort Bs[2 * 128 * 64];
  const int tid = threadIdx.x, lane = tid & 63, wv = tid >> 6;
  const int wm = wv >> 1, wn = wv & 1;
  int bx = blockIdx.x, by = blockIdx.y;
  const long bm = (long)bx * 128, bn = (long)by * 128;
  int z = blockIdx.z, zq = z, zr = 0;
  if (ZD > 1) { zq = z / ZD; zr = z - zq * ZD; }
  const ushort* Ap = A + (long)zq * sAq + (long)zr * sAr + bm * lda;
  ushort* Cp = C + (long)zq * sCq + (long)zr * sCr;
  const int nt = K >> 6;

  const int srow = wv * 32 + (lane >> 3);
  const int scol = ((lane & 7) ^ (srow & 7)) << 3;
  const ushort* apb = Ap + (long)srow * lda + scol;

  if (BSRC == 1) {
    // ---- nt==1 path: stage A via gl16; B from f32 via reg-convert ----
    const float* Bf = (const float*)Bv + (long)zq * sBq + (long)zr * sBr + bn * ldb;
    #pragma unroll
    for (int i_ = 0; i_ < 4; ++i_)
      gl16(apb + (long)(i_ * 8) * lda, &As[(wv * 32) * 64] + i_ * 512);
    #pragma unroll
    for (int i = 0; i < 4; ++i) {
      int row = (tid >> 3) + 32 * i;
      int b8 = tid & 7;
      ushort u[8];
      if (bn + row < N) {
        const float* p = Bf + (long)row * ldb + b8 * 8;
        f4 v0 = *(const f4*)p, v1 = *(const f4*)(p + 4);
        u[0] = f2b(v0[0]); u[1] = f2b(v0[1]); u[2] = f2b(v0[2]); u[3] = f2b(v0[3]);
        u[4] = f2b(v1[0]); u[5] = f2b(v1[1]); u[6] = f2b(v1[2]); u[7] = f2b(v1[3]);
      } else {
        #pragma unroll
        for (int j = 0; j < 8; ++j) u[j] = 0;
      }
      *(int4*)(&Bs[row * 64 + ((b8 ^ (row & 7)) << 3)]) = *(int4*)u;
    }
    WAIT_VM(0);
    WAIT_LGKM0;
    RAWBAR;
  } else {
    const ushort* Bp = (const ushort*)Bv + (long)zq * sBq + (long)zr * sBr + bn * ldb;
    const ushort* bpb = Bp + (long)srow * ldb + scol;
    #define STAGE(T, D) { \
      const ushort* ap_ = apb + (T) * 64; \
      const ushort* bp_ = bpb + (T) * 64; \
      ushort* la_ = &As[((D) * 128 + wv * 32) * 64]; \
      ushort* lb_ = &Bs[((D) * 128 + wv * 32) * 64]; \
      _Pragma("unroll") \
      for (int i_ = 0; i_ < 4; ++i_) gl16(ap_ + (long)(i_ * 8) * lda, la_ + i_ * 512); \
      _Pragma("unroll") \
      for (int i_ = 0; i_ < 4; ++i_) gl16(bp_ + (long)(i_ * 8) * ldb, lb_ + i_ * 512); \
    }
    STAGE(0, 0);
    if (nt > 1) { STAGE(1, 1); WAIT_VM(8); }
    else        { WAIT_VM(0); }
    RAWBAR;
    f4 acc[4][4] = {};
    for (int t = 0; t < nt; ++t) {
      const int d = t & 1;
      const ushort* as = As + d * 8192;
      const ushort* bs = Bs + d * 8192;
      bf8 af[4][2], bfv[4][2];
      #pragma unroll
      for (int mi = 0; mi < 4; ++mi) {
        int r = wm * 64 + mi * 16 + (lane & 15);
        #pragma unroll
        for (int kk = 0; kk < 2; ++kk) {
          int blk = kk * 4 + (lane >> 4);
          af[mi][kk] = *(const bf8*)(as + r * 64 + ((blk ^ (r & 7)) << 3));
        }
      }
      #pragma unroll
      for (int ni = 0; ni < 4; ++ni) {
        int r = wn * 64 + ni * 16 + (lane & 15);
        #pragma unroll
        for (int kk = 0; kk < 2; ++kk) {
          int blk = kk * 4 + (lane >> 4);
          bfv[ni][kk] = *(const bf8*)(bs + r * 64 + ((blk ^ (r & 7)) << 3));
        }
      }
      WAIT_LGKM0;
      RAWBAR;
      if (t + 2 < nt) STAGE(t + 2, d);
      #pragma unroll
      for (int kk = 0; kk < 2; ++kk)
        #pragma unroll
        for (int mi = 0; mi < 4; ++mi)
          #pragma unroll
          for (int ni = 0; ni < 4; ++ni)
            acc[mi][ni] = __builtin_amdgcn_mfma_f32_16x16x32_bf16(af[mi][kk], bfv[ni][kk], acc[mi][ni], 0, 0, 0);
      if (t + 1 < nt) {
        if (t + 2 < nt) { WAIT_VM(8); }
        else            { WAIT_VM(0); }
        RAWBAR;
      }
    }
    #undef STAGE
    #pragma unroll
    for (int mi = 0; mi < 4; ++mi)
      #pragma unroll
      for (int ni = 0; ni < 4; ++ni) {
        int col = (int)bn + wn * 64 + ni * 16 + (lane & 15);
        if (col < N) {
          #pragma unroll
          for (int rr = 0; rr < 4; ++rr) {
            int row = (int)bm + wm * 64 + mi * 16 + (lane >> 4) * 4 + rr;
            float v = acc[mi][ni][rr];
            if (BIASMODE == 1) v += bias[col & biasMask];
            if (BIASMODE == 2) v += bias[row & biasMask];
            if (RELU) v = fmaxf(v, 0.f);
            Cp[(long)row * ldc + col] = f2b(v);
          }
        }
      }
    return;
  }

  // ---- BSRC==1 compute (single K-tile) ----
  f4 acc[4][4] = {};
  {
    const ushort* as = As;
    const ushort* bs = Bs;
    bf8 af[4][2], bfv[4][2];
    #pragma unroll
    for (int mi = 0; mi < 4; ++mi) {
      int r = wm * 64 + mi * 16 + (lane & 15);
      #pragma unroll
      for (int kk = 0; kk < 2; ++kk) {
        int blk = kk * 4 + (lane >> 4);
        af[mi][kk] = *(const bf8*)(as + r * 64 + ((blk ^ (r & 7)) << 3));
      }
    }
    #pragma unroll
    for (int ni = 0; ni < 4; ++ni) {
      int r = wn * 64 + ni * 16 + (lane & 15);
      #pragma unroll
      for (int kk = 0; kk < 2; ++kk) {
        int blk = kk * 4 + (lane >> 4);
        bfv[ni][kk] = *(const bf8*)(bs + r * 64 + ((blk ^ (r & 7)) << 3));
      }
    }
    WAIT_LGKM0;
    #pragma unroll
    for (int kk = 0; kk < 2; ++kk)
      #pragma unroll
      for (int mi = 0; mi < 4; ++mi)
        #pragma unroll
        for (int ni = 0; ni < 4; ++ni)
          acc[mi][ni] = __builtin_amdgcn_mfma_f32_16x16x32_bf16(af[mi][kk], bfv[ni][kk], acc[mi][ni], 0, 0, 0);
  }
  #pragma unroll
  for (int mi = 0; mi < 4; ++mi)
    #pragma unroll
    for (int ni = 0; ni < 4; ++ni) {
      int col = (int)bn + wn * 64 + ni * 16 + (lane & 15);
      if (col < N) {
        #pragma unroll
        for (int rr = 0; rr < 4; ++rr) {
          int row = (int)bm + wm * 64 + mi * 16 + (lane >> 4) * 4 + rr;
          float v = acc[mi][ni][rr];
          if (BIASMODE == 1) v += bias[col & biasMask];
          if (BIASMODE == 2) v += bias[row & biasMask];
          if (RELU) v = fmaxf(v, 0.f);
          Cp[(long)row * ldc + col] = f2b(v);
        }
      }
    }
}

// ------------- split-K thin GEMM: M=128 tiles, bf16 partial output ---------
__global__ __launch_bounds__(256) void gemmsk_k(
    const ushort* __restrict__ A, const ushort* __restrict__ B,
    ushort* __restrict__ P, int Kc, int lda, int ldb,
    long sAq, long sBq)
{
  __shared__ __align__(16) ushort As[2 * 128 * 64];
  __shared__ __align__(16) ushort Bs[2 * 128 * 64];
  const int tid = threadIdx.x, lane = tid & 63, wv = tid >> 6;
  const int wm = wv >> 1, wn = wv & 1;
  const long bm = (long)blockIdx.x * 128, bn = (long)blockIdx.y * 128;
  const int kc = blockIdx.z & 3, zq = blockIdx.z >> 2;
  const ushort* Ap = A + (long)zq * sAq + kc * Kc + bm * lda;
  const ushort* Bp = B + (long)zq * sBq + kc * Kc + bn * ldb;
  const int nt = Kc >> 6;

  const int srow = wv * 32 + (lane >> 3);
  const int scol = ((lane & 7) ^ (srow & 7)) << 3;
  const ushort* apb = Ap + (long)srow * lda + scol;
  const ushort* bpb = Bp + (long)srow * ldb + scol;

  #define STAGEK(T, D) { \
    const ushort* ap_ = apb + (T) * 64; \
    const ushort* bp_ = bpb + (T) * 64; \
    ushort* la_ = &As[((D) * 128 + wv * 32) * 64]; \
    ushort* lb_ = &Bs[((D) * 128 + wv * 32) * 64]; \
    _Pragma("unroll") \
    for (int i_ = 0; i_ < 4; ++i_) gl16(ap_ + (long)(i_ * 8) * lda, la_ + i_ * 512); \
    _Pragma("unroll") \
    for (int i_ = 0; i_ < 4; ++i_) gl16(bp_ + (long)(i_ * 8) * ldb, lb_ + i_ * 512); \
  }

  STAGEK(0, 0);
  if (nt > 1) { STAGEK(1, 1); WAIT_VM(8); }
  else        { WAIT_VM(0); }
  RAWBAR;

  f4 acc[4][4] = {};
  for (int t = 0; t < nt; ++t) {
    const int d = t & 1;
    const ushort* as = As + d * 8192;
    const ushort* bs = Bs + d * 8192;
    bf8 af[4][2], bfv[4][2];
    #pragma unroll
    for (int mi = 0; mi < 4; ++mi) {
      int r = wm * 64 + mi * 16 + (lane & 15);
      #pragma unroll
      for (int kk = 0; kk < 2; ++kk) {
        int blk = kk * 4 + (lane >> 4);
        af[mi][kk] = *(const bf8*)(as + r * 64 + ((blk ^ (r & 7)) << 3));
      }
    }
    #pragma unroll
    for (int ni = 0; ni < 4; ++ni) {
      int r = wn * 64 + ni * 16 + (lane & 15);
      #pragma unroll
      for (int kk = 0; kk < 2; ++kk) {
        int blk = kk * 4 + (lane >> 4);
        bfv[ni][kk] = *(const bf8*)(bs + r * 64 + ((blk ^ (r & 7)) << 3));
      }
    }
    WAIT_LGKM0;
    RAWBAR;
    if (t + 2 < nt) STAGEK(t + 2, d);
    #pragma unroll
    for (int kk = 0; kk < 2; ++kk)
      #pragma unroll
      for (int mi = 0; mi < 4; ++mi)
        #pragma unroll
        for (int ni = 0; ni < 4; ++ni)
          acc[mi][ni] = __builtin_amdgcn_mfma_f32_16x16x32_bf16(af[mi][kk], bfv[ni][kk], acc[mi][ni], 0, 0, 0);
    if (t + 1 < nt) {
      if (t + 2 < nt) { WAIT_VM(8); }
      else            { WAIT_VM(0); }
      RAWBAR;
    }
  }
  #undef STAGEK

  ushort* Pp = P + (long)blockIdx.z * 131072;
  #pragma unroll
  for (int mi = 0; mi < 4; ++mi)
    #pragma unroll
    for (int ni = 0; ni < 4; ++ni) {
      int col = (int)bn + wn * 64 + ni * 16 + (lane & 15);
      #pragma unroll
      for (int rr = 0; rr < 4; ++rr) {
        int row = (int)bm + wm * 64 + mi * 16 + (lane >> 4) * 4 + rr;
        Pp[(long)row * 1024 + col] = f2b(acc[mi][ni][rr]);
      }
    }
}

// ------------- split-K reduce: sum 4 bf16 partial slabs -> bf16 -------------
template<int RELU>
__global__ __launch_bounds__(256) void redk_k(const ushort* __restrict__ P,
                                              ushort* __restrict__ C) {
  int idx = blockIdx.x * 256 + threadIdx.x;   // 262144 (8z x 32768 groups of 4)
  long z = idx >> 15;
  long rem = (long)(idx & 32767) * 4;
  const ushort* base = P + z * 4 * 131072 + rem;
  float s[4] = {0.f, 0.f, 0.f, 0.f};
  #pragma unroll
  for (int kc = 0; kc < 4; ++kc) {
    ushort4 v = *(const ushort4*)(base + kc * 131072);
    s[0] += b2f(v.x); s[1] += b2f(v.y); s[2] += b2f(v.z); s[3] += b2f(v.w);
  }
  ushort4 o;
  #pragma unroll
  for (int j = 0; j < 4; ++j) {
    float v = s[j];
    if (RELU) v = fmaxf(v, 0.f);
    ((ushort*)&o)[j] = f2b(v);
  }
  *(ushort4*)(C + z * 131072 + rem) = o;
}

// ---------------- fused 2-layer GRU, register-carried h ----------------
__global__ __launch_bounds__(256, 2) void gru_k(
    const ushort* __restrict__ xT,   // (32, 8192, 64)
    const float* __restrict__ Wx0, const float* __restrict__ Wh0,
    const float* __restrict__ bx0, const float* __restrict__ bh0,
    const float* __restrict__ Wx1, const float* __restrict__ Wh1,
    const float* __restrict__ bx1, const float* __restrict__ bh1,
    ushort* __restrict__ rout)       // (8192, 32, 64)
{
  __shared__ ushort hbf[2][2][1024];   // [layer][buf][16*64], XOR-swizzled
  const int tid = threadIdx.x, lane = tid & 63, w = tid >> 6;
  const int seq0 = blockIdx.x * 16;
  for (int i = tid; i < 4096; i += 256) ((ushort*)hbf)[i] = 0;

  const float* Wxp[2] = {Wx0, Wx1};
  const float* Whp[2] = {Wh0, Wh1};
  const float* bxp[2] = {bx0, bx1};
  const float* bhp[2] = {bh0, bh1};
  bf8 Wxf[2][3][2], Whf[2][3][2];
  float bxv[2][3], bhv[2][3];
  #pragma unroll
  for (int L = 0; L < 2; ++L)
    #pragma unroll
    for (int g = 0; g < 3; ++g) {
      int row = g * 64 + w * 16 + (lane & 15);
      bxv[L][g] = bxp[L][row];
      bhv[L][g] = bhp[L][row];
      #pragma unroll
      for (int kk = 0; kk < 2; ++kk) {
        int kb = kk * 32 + (lane >> 4) * 8;
        Wxf[L][g][kk] = pack8(Wxp[L] + row * 64 + kb);
        Whf[L][g][kk] = pack8(Whp[L] + row * 64 + kb);
      }
    }
  __syncthreads();

  const int arow = lane & 15;
  const int col = w * 16 + (lane & 15);
  f4 hprev[2] = {{0.f,0.f,0.f,0.f},{0.f,0.f,0.f,0.f}};
  int pv = 0;
  for (int t = 0; t < 32; ++t) {
    const int cur = pv ^ 1;
    #pragma unroll
    for (int L = 0; L < 2; ++L) {
      bf8 axf[2], ahf[2];
      if (L == 0) {
        const ushort* xb = xT + ((long)t * 8192 + seq0 + arow) * 64 + (lane >> 4) * 8;
        axf[0] = *(const bf8*)(xb);
        axf[1] = *(const bf8*)(xb + 32);
      } else {
        #pragma unroll
        for (int kk = 0; kk < 2; ++kk) {
          int blk = kk * 4 + (lane >> 4);
          axf[kk] = *(const bf8*)(&hbf[0][cur][arow * 64 + ((blk ^ (arow & 7)) << 3)]);
        }
      }
      #pragma unroll
      for (int kk = 0; kk < 2; ++kk) {
        int blk = kk * 4 + (lane >> 4);
        ahf[kk] = *(const bf8*)(&hbf[L][pv][arow * 64 + ((blk ^ (arow & 7)) << 3)]);
      }
      f4 aX[3] = {}; f4 aH[3] = {};
      #pragma unroll
      for (int kk = 0; kk < 2; ++kk)
        #pragma unroll
        for (int g = 0; g < 3; ++g) {
          aX[g] = __builtin_amdgcn_mfma_f32_16x16x32_bf16(axf[kk], Wxf[L][g][kk], aX[g], 0, 0, 0);
          aH[g] = __builtin_amdgcn_mfma_f32_16x16x32_bf16(ahf[kk], Whf[L][g][kk], aH[g], 0, 0, 0);
        }
      f4 hn;
      #pragma unroll
      for (int r = 0; r < 4; ++r) {
        float rg = sigm(aX[0][r] + bxv[L][0] + aH[0][r] + bhv[L][0]);
        float zg = sigm(aX[1][r] + bxv[L][1] + aH[1][r] + bhv[L][1]);
        float cand = tanh_f(aX[2][r] + bxv[L][2] + rg * (aH[2][r] + bhv[L][2]));
        hn[r] = (1.f - zg) * cand + zg * hprev[L][r];
      }
      hprev[L] = hn;
      #pragma unroll
      for (int r = 0; r < 4; ++r) {
        int row = (lane >> 4) * 4 + r;
        ushort hb = f2b(hn[r]);
        hbf[L][cur][row * 64 + (((col >> 3) ^ (row & 7)) << 3) + (col & 7)] = hb;
        if (L == 1) rout[((long)(seq0 + row) * 32 + t) * 64 + col] = hb;
      }
      __syncthreads();
    }
    pv = cur;
  }
}

// ------------- fused temporal attention + residual + LayerNorm -------------
__global__ __launch_bounds__(256) void attn_k(
    const ushort* __restrict__ r,
    const float* __restrict__ Wq, const float* __restrict__ Wk,
    const float* __restrict__ Wv, const float* __restrict__ Wo,
    const float* __restrict__ lng, const float* __restrict__ lnb,
    ushort* __restrict__ enc)
{
  __shared__ ushort q_s[4][32][40];
  __shared__ ushort k_s[4][32][40];
  __shared__ ushort v_s[4][16][40];
  __shared__ ushort p_s[4][32][40];
  __shared__ ushort o_s[32][88];
  __shared__ float  ln_s[32][68];
  const int tid = threadIdx.x, lane = tid & 63, w = tid >> 6;
  const long n = blockIdx.x;

  for (int i = tid; i < 4 * 32 * 40; i += 256) { ((ushort*)q_s)[i] = 0; ((ushort*)k_s)[i] = 0; }

  bf8 wqf[2], wkf[2], wvf[2], wof[2];
  #pragma unroll
  for (int kk = 0; kk < 2; ++kk) {
    int row = w * 16 + (lane & 15);
    int kb = kk * 32 + (lane >> 4) * 8;
    wqf[kk] = pack8(Wq + row * 64 + kb);
    wkf[kk] = pack8(Wk + row * 64 + kb);
    wvf[kk] = pack8(Wv + row * 64 + kb);
    wof[kk] = pack8(Wo + row * 64 + kb);
  }
  __syncthreads();

  bf8 ar[2][2];
  #pragma unroll
  for (int mi = 0; mi < 2; ++mi)
    #pragma unroll
    for (int kk = 0; kk < 2; ++kk)
      ar[mi][kk] = *(const bf8*)(r + (n * 32 + mi * 16 + (lane & 15)) * 64 + kk * 32 + (lane >> 4) * 8);
  f4 aq[2] = {}, ak[2] = {}, av[2] = {};
  #pragma unroll
  for (int kk = 0; kk < 2; ++kk)
    #pragma unroll
    for (int mi = 0; mi < 2; ++mi) {
      aq[mi] = __builtin_amdgcn_mfma_f32_16x16x32_bf16(ar[mi][kk], wqf[kk], aq[mi], 0, 0, 0);
      ak[mi] = __builtin_amdgcn_mfma_f32_16x16x32_bf16(ar[mi][kk], wkf[kk], ak[mi], 0, 0, 0);
      av[mi] = __builtin_amdgcn_mfma_f32_16x16x32_bf16(ar[mi][kk], wvf[kk], av[mi], 0, 0, 0);
    }
  #pragma unroll
  for (int mi = 0; mi < 2; ++mi)
    #pragma unroll
    for (int rr = 0; rr < 4; ++rr) {
      int row = mi * 16 + (lane >> 4) * 4 + rr;
      q_s[w][row][lane & 15] = f2b(aq[mi][rr]);
      k_s[w][row][lane & 15] = f2b(ak[mi][rr]);
      v_s[w][lane & 15][row] = f2b(av[mi][rr]);
    }

  bf8 a_q[2], b_k[2];
  #pragma unroll
  for (int mt = 0; mt < 2; ++mt)
    a_q[mt] = *(const bf8*)(&q_s[w][mt * 16 + (lane & 15)][(lane >> 4) * 8]);
  #pragma unroll
  for (int nt = 0; nt < 2; ++nt)
    b_k[nt] = *(const bf8*)(&k_s[w][nt * 16 + (lane & 15)][(lane >> 4) * 8]);
  f4 s_[2][2] = {};
  #pragma unroll
  for (int mt = 0; mt < 2; ++mt)
    #pragma unroll
    for (int nt = 0; nt < 2; ++nt)
      s_[mt][nt] = __builtin_amdgcn_mfma_f32_16x16x32_bf16(a_q[mt], b_k[nt], s_[mt][nt], 0, 0, 0);
  #pragma unroll
  for (int mt = 0; mt < 2; ++mt)
    #pragma unroll
    for (int rr = 0; rr < 4; ++rr) {
      int trow = mt * 16 + (lane >> 4) * 4 + rr;
      float s0 = s_[mt][0][rr] * 0.25f, s1 = s_[mt][1][rr] * 0.25f;
      int c0 = lane & 15, c1 = 16 + (lane & 15);
      if (c0 > trow) s0 = -1e30f;
      if (c1 > trow) s1 = -1e30f;
      float m = fmaxf(s0, s1);
      #pragma unroll
      for (int d = 1; d < 16; d <<= 1) m = fmaxf(m, __shfl_xor(m, d));
      float e0 = __expf(s0 - m), e1 = __expf(s1 - m);
      float sum = e0 + e1;
      #pragma unroll
      for (int d = 1; d < 16; d <<= 1) sum += __shfl_xor(sum, d);
      float inv = 1.f / sum;
      p_s[w][trow][c0] = f2b(e0 * inv);
      p_s[w][trow][c1] = f2b(e1 * inv);
    }

  bf8 b_v = *(const bf8*)(&v_s[w][lane & 15][(lane >> 4) * 8]);
  f4 o_[2] = {};
  #pragma unroll
  for (int mt = 0; mt < 2; ++mt) {
    bf8 a_p = *(const bf8*)(&p_s[w][mt * 16 + (lane & 15)][(lane >> 4) * 8]);
    o_[mt] = __builtin_amdgcn_mfma_f32_16x16x32_bf16(a_p, b_v, o_[mt], 0, 0, 0);
  }
  #pragma unroll
  for (int mt = 0; mt < 2; ++mt)
    #pragma unroll
    for (int rr = 0; rr < 4; ++rr)
      o_s[mt * 16 + (lane >> 4) * 4 + rr][w * 16 + (lane & 15)] = f2b(o_[mt][rr]);
  __syncthreads();

  bf8 a_o[2][2];
  #pragma unroll
  for (int mt = 0; mt < 2; ++mt)
    #pragma unroll
    for (int kk = 0; kk < 2; ++kk)
      a_o[mt][kk] = *(const bf8*)(&o_s[mt * 16 + (lane & 15)][kk * 32 + (lane >> 4) * 8]);
  f4 oo[2] = {};
  #pragma unroll
  for (int kk = 0; kk < 2; ++kk)
    #pragma unroll
    for (int mt = 0; mt < 2; ++mt)
      oo[mt] = __builtin_amdgcn_mfma_f32_16x16x32_bf16(a_o[mt][kk], wof[kk], oo[mt], 0, 0, 0);
  #pragma unroll
  for (int mt = 0; mt < 2; ++mt)
    #pragma unroll
    for (int rr = 0; rr < 4; ++rr) {
      int row = mt * 16 + (lane >> 4) * 4 + rr;
      int col = w * 16 + (lane & 15);
      float resid = b2f(r[(n * 32 + row) * 64 + col]);
      ln_s[row][col] = oo[mt][rr] + resid;
    }
  __syncthreads();

  {
    int row = tid >> 3, seg = tid & 7;
    float vals[8], sm = 0.f, sq = 0.f;
    #pragma unroll
    for (int j = 0; j < 8; ++j) {
      float v = ln_s[row][seg * 8 + j];
      vals[j] = v; sm += v; sq += v * v;
    }
    #pragma unroll
    for (int d = 1; d < 8; d <<= 1) { sm += __shfl_xor(sm, d); sq += __shfl_xor(sq, d); }
    float mu = sm * (1.f / 64.f);
    float var = sq * (1.f / 64.f) - mu * mu;
    float rs = rsqrtf(var + 1e-6f);
    union { ushort u[8]; int4 v; } ou;
    #pragma unroll
    for (int j = 0; j < 8; ++j) {
      int c = seg * 8 + j;
      ou.u[j] = f2b((vals[j] - mu) * rs * lng[c] + lnb[c]);
    }
    *(int4*)(enc + (n * 32 + row) * 64 + seg * 8) = ou.v;
  }
}

// ------------- final: out[(b,s),c] = sum_d hg3aT[b][d][s] * Wfin[d,c] -------
__global__ __launch_bounds__(256) void final2_k(const ushort* __restrict__ hg3aT,
                                                const float* __restrict__ wf,
                                                float* __restrict__ out) {
  int i = blockIdx.x * 256 + threadIdx.x;  // 8192
  int b = i >> 10, s = i & 1023;
  const ushort* base = hg3aT + (long)b * 131072 + s;
  float a0 = 0.f, a1 = 0.f;
  #pragma unroll
  for (int d = 0; d < 128; ++d) {
    float v = b2f(base[d * 1024]);
    a0 += v * wf[2 * d];
    a1 += v * wf[2 * d + 1];
  }
  out[2 * i] = a0; out[2 * i + 1] = a1;
}

extern "C" void kernel_launch(void* const* d_in, const int* in_sizes, int n_in,
                              void* d_out, int out_size, void* d_ws, size_t ws_size,
                              hipStream_t stream) {
  const float* src = (const float*)d_in[0];
  const float* H   = (const float*)d_in[1];
  const float* adj = (const float*)d_in[2];
  const float* gW1 = (const float*)d_in[4];
  const float* gb1 = (const float*)d_in[5];
  const float* gW2 = (const float*)d_in[6];
  const float* gb2 = (const float*)d_in[7];
  const float* Wm  = (const float*)d_in[8];
  const float* bm  = (const float*)d_in[9];
  const float* Wl  = (const float*)d_in[10];
  const float* bl  = (const float*)d_in[11];
  const float* Wx0 = (const float*)d_in[12];
  const float* Wh0 = (const float*)d_in[13];
  const float* bx0 = (const float*)d_in[14];
  const float* bh0 = (const float*)d_in[15];
  const float* Wx1 = (const float*)d_in[16];
  const float* Wh1 = (const float*)d_in[17];
  const float* bx1 = (const float*)d_in[18];
  const float* bh1 = (const float*)d_in[19];
  const float* Wq  = (const float*)d_in[20];
  const float* Wk  = (const float*)d_in[21];
  const float* Wv  = (const float*)d_in[22];
  const float* Wo  = (const float*)d_in[23];
  const float* lng = (const float*)d_in[24];
  const float* lnb = (const float*)d_in[25];
  const float* Wg1 = (const float*)d_in[26];
  const float* Wg2 = (const float*)d_in[27];
  const float* Wp  = (const float*)d_in[28];

  char* ws = (char*)d_ws;
  const size_t MB = 1048576ull;
  ushort* adj_bf  = (ushort*)(ws);                  // 0-2
  ushort* Hnew_bf = (ushort*)(ws + 2 * MB);         // 2-4
  ushort* H_bf    = (ushort*)(ws + 4 * MB);
  ushort* Wm_bf   = (ushort*)(ws + 4 * MB + 262144);
  ushort* W1T     = (ushort*)(ws + 4 * MB + 524288);
  ushort* WcT     = (ushort*)(ws + 4 * MB + 524288 + 16384);
  float*  bc      = (float*) (ws + 4 * MB + 524288 + 32768);
  float*  wfin    = (float*) (ws + 4 * MB + 524288 + 33792);
  ushort* Wg1T    = (ushort*)(ws + 5 * MB);         // 5-6
  ushort* adjcat  = (ushort*)(ws + 6 * MB);         // 6-10
  ushort* XT      = (ushort*)(ws + 38 * MB);        // 38-102 (dead after layer-1)
  ushort* xT      = (ushort*)(ws + 38 * MB);        // 38-70 over XT (layer-2 out)
  ushort* r_bf    = (ushort*)(ws + 70 * MB);        // 70-102
  ushort* h1cat   = (ushort*)(ws + 102 * MB);       // 102-230 (dead after layer-2)
  ushort* enc     = (ushort*)(ws + 102 * MB);       // 102-134 over h1cat head
  ushort* Pk      = (ushort*)(ws + 134 * MB);       // 134-142 (bf16 partials)
  ushort* g1T     = (ushort*)(ws + 150 * MB);       // 150-152
  ushort* hgT     = (ushort*)(ws + 152 * MB);       // 152-154
  ushort* hg3aT   = (ushort*)(ws + 154 * MB);       // 154-156

  auto CVT = [&](const float* in, ushort* out, int n) {
    int n4 = n >> 2;
    cvt_k<<<dim3((n4 + 255) / 256), dim3(256), 0, stream>>>(in, out, n4);
  };
  CVT(adj, adj_bf, 1048576);
  CVT(H, H_bf, 131072);
  CVT(Wm, Wm_bf, 131072);
  cvtT_k<<<dim3(1, 2), 256, 0, stream>>>(gW1, W1T, 64, 128);
  cvtT_k<<<dim3(32, 2), 256, 0, stream>>>(Wg1, Wg1T, 2048, 128);
  wcombT_k<<<dim3(32), 256, 0, stream>>>(Wl, gW2, WcT);
  biasc_k<<<dim3(1), 64, 0, stream>>>(gb2, Wl, bl, bc);
  wfin_k<<<dim3(1), 256, 0, stream>>>(Wg2, Wp, wfin);

  // H_new = H @ Wm^T + bm  (fills second half of the stacked B)
  gemm2_k<1,0,0,0><<<dim3(8,8,1),256,0,stream>>>(H_bf, Wm_bf, Hnew_bf, bm, 1023,
      1024, 128, 128, 128, 1024, 1, 0,0, 0,0, 0,0);
  // XT[b][t][h][s] = (src@W1)^T — B = f32 src, converted during staging (nt==1)
  gemm2_k<0,0,0,1><<<dim3(1,8,256),256,0,stream>>>(W1T, src, XT, nullptr, 0,
      1024, 64, 64, 2048, 1024, 32, 0,0, 2097152,64, 4194304,131072);
  // adjcat[s'] = [adj[s'] | Hnew[s']]
  cat_k<<<dim3(512),256,0,stream>>>(adj_bf, Hnew_bf, adjcat);
  // layer-1 props fused: h1cat = relu(XT @ [adj;Hnew]^T + b1), BK=32 kernel
  gemm4_k<2,1><<<dim3(16,8,8),512,0,stream>>>(XT, adj_bf, h1cat, gb1, 127,
      2048, 1024, 1024, 1024, 2048, 4194304, 0, 8388608);
  // layer-2 props fused (K=2048) + fused x-projection -> xT (t, seq, h)
  gemm3_k<0,0,3><<<dim3(16,4,8),512,0,stream>>>(h1cat, adjcat, xT, nullptr, 0,
      1024, 2048, 2048, 2048, 0, 8388608, 0, 0, WcT, bc);
  // 2-layer GRU (register-carried h)
  gru_k<<<dim3(512),dim3(256),0,stream>>>(xT, Wx0,Wh0,bx0,bh0, Wx1,Wh1,bx1,bh1, r_bf);
  // fused attention + residual + LN -> enc
  attn_k<<<dim3(8192),dim3(256),0,stream>>>(r_bf, Wq,Wk,Wv,Wo, lng,lnb, enc);
  // HGN via split-K x4 (256 blocks each, bf16 partials) + reduce
  gemmsk_k<<<dim3(1,8,32),256,0,stream>>>(Wg1T, enc, Pk, 512, 2048, 2048, 0, 2097152);
  redk_k<0><<<dim3(1024),256,0,stream>>>(Pk, g1T);
  gemmsk_k<<<dim3(1,8,32),256,0,stream>>>(g1T, adj_bf, Pk, 256, 1024, 1024, 131072, 0);
  redk_k<1><<<dim3(1024),256,0,stream>>>(Pk, hgT);
  gemmsk_k<<<dim3(1,8,32),256,0,stream>>>(hgT, adj_bf, Pk, 256, 1024, 1024, 131072, 0);
  redk_k<0><<<dim3(1024),256,0,stream>>>(Pk, hg3aT);
  final2_k<<<dim3(32),256,0,stream>>>(hg3aT, wfin, (float*)d_out);
}

// Round 17
// 571.633 us; speedup vs baseline: 1.0240x; 1.0240x over previous
//
#include <hip/hip_runtime.h>

typedef __attribute__((ext_vector_type(8))) short bf8;
typedef __attribute__((ext_vector_type(4))) float f4;

__device__ __forceinline__ ushort f2b(float f) {
  union { float f; unsigned u; } v; v.f = f;
  unsigned u = v.u + 0x7FFFu + ((v.u >> 16) & 1u);
  return (ushort)(u >> 16);
}
__device__ __forceinline__ float b2f(ushort h) {
  union { unsigned u; float f; } v; v.u = ((unsigned)h) << 16; return v.f;
}
__device__ __forceinline__ bf8 pack8(const float* p) {
  f4 a = *(const f4*)p; f4 b = *(const f4*)(p + 4);
  bf8 t;
  t[0] = (short)f2b(a[0]); t[1] = (short)f2b(a[1]);
  t[2] = (short)f2b(a[2]); t[3] = (short)f2b(a[3]);
  t[4] = (short)f2b(b[0]); t[5] = (short)f2b(b[1]);
  t[6] = (short)f2b(b[2]); t[7] = (short)f2b(b[3]);
  return t;
}
__device__ __forceinline__ float sigm(float x) { return 1.f / (1.f + __expf(-x)); }
__device__ __forceinline__ float tanh_f(float x) {
  float a = fabsf(x), e = __expf(-2.f * a);
  return copysignf((1.f - e) / (1.f + e), x);
}

__device__ __forceinline__ void gl16(const void* g, void* l) {
  __builtin_amdgcn_global_load_lds(
      (const __attribute__((address_space(1))) unsigned int*)(uintptr_t)g,
      (__attribute__((address_space(3))) unsigned int*)(uintptr_t)l, 16, 0, 0);
}

#define SFENCE __builtin_amdgcn_sched_barrier(0)
#define RAWBAR { __builtin_amdgcn_s_barrier(); SFENCE; }
#define WAIT_LGKM0 { asm volatile("s_waitcnt lgkmcnt(0)" ::: "memory"); SFENCE; }
#define WAIT_VM(n) { asm volatile("s_waitcnt vmcnt(" #n ")" ::: "memory"); SFENCE; }

// ---------------- f32 -> bf16 convert ----------------
__global__ __launch_bounds__(256) void cvt_k(const float* __restrict__ in,
                                             ushort* __restrict__ out, int n4) {
  int i = blockIdx.x * 256 + threadIdx.x;
  if (i < n4) {
    f4 v = ((const f4*)in)[i];
    ushort4 o;
    o.x = f2b(v[0]); o.y = f2b(v[1]); o.z = f2b(v[2]); o.w = f2b(v[3]);
    ((ushort4*)out)[i] = o;
  }
}

// ---------------- f32 -> bf16 transposing convert: in (R,C) -> out (C,R) ----
__global__ __launch_bounds__(256) void cvtT_k(const float* __restrict__ in,
                                              ushort* __restrict__ out, int R, int C) {
  __shared__ ushort t[64][68];
  const int tid = threadIdx.x;
  const int r0 = blockIdx.x * 64, c0 = blockIdx.y * 64;
  #pragma unroll
  for (int it = 0; it < 4; ++it) {
    int r = (tid >> 4) + 16 * it, c = (tid & 15) * 4;
    f4 v = *(const f4*)(in + (long)(r0 + r) * C + c0 + c);
    #pragma unroll
    for (int j = 0; j < 4; ++j) t[c + j][r] = f2b(v[j]);
  }
  __syncthreads();
  #pragma unroll
  for (int it = 0; it < 4; ++it) {
    int cc = (tid >> 4) + 16 * it, rr = (tid & 15) * 4;
    ushort4 o = { t[cc][rr], t[cc][rr + 1], t[cc][rr + 2], t[cc][rr + 3] };
    *(ushort4*)(out + (long)(c0 + cc) * R + r0 + rr) = o;
  }
}

// ---------------- per-row concat: o[s] = [a[s] | h[s]]  (1024 x 2048) ------
__global__ __launch_bounds__(256) void cat_k(const ushort* __restrict__ a,
                                             const ushort* __restrict__ h,
                                             ushort* __restrict__ o) {
  int i = blockIdx.x * 256 + threadIdx.x;      // 131072
  int s = i >> 7, c8 = (i & 127) << 3;
  *(int4*)(o + (long)s * 2048 + c8) = *(const int4*)(a + (long)s * 1024 + c8);
  *(int4*)(o + (long)s * 2048 + 1024 + c8) = *(const int4*)(h + (long)s * 1024 + c8);
}

// ---------------- tiny weight-fusion kernels ----------------
__global__ void wcombT_k(const float* __restrict__ Wl, const float* __restrict__ W2,
                         ushort* __restrict__ out) {
  int idx = blockIdx.x * 256 + threadIdx.x;  // 8192
  int d = idx >> 7, h = idx & 127;
  float s = 0.f;
  #pragma unroll
  for (int f = 0; f < 64; ++f) s += Wl[d * 64 + f] * W2[h * 64 + f];
  out[d * 128 + h] = f2b(s);
}
__global__ void biasc_k(const float* __restrict__ gb2, const float* __restrict__ Wl,
                        const float* __restrict__ bl, float* __restrict__ bc) {
  int d = threadIdx.x;  // 64
  float s = 0.f;
  #pragma unroll
  for (int f = 0; f < 64; ++f) s += gb2[f] * Wl[d * 64 + f];
  bc[d] = 2.f * s + bl[d];
}
__global__ void wfin_k(const float* __restrict__ Wg2, const float* __restrict__ Wp,
                       float* __restrict__ wf) {
  int idx = threadIdx.x;  // 256
  int d = idx >> 1, c = idx & 1;
  float s = 0.f;
  #pragma unroll
  for (int e = 0; e < 128; ++e) s += Wg2[d * 128 + e] * Wp[c * 128 + e];
  wf[idx] = s;
}

// ============ 256x256-tile bf16 MFMA GEMM, 8 waves, dbuf + counted vmcnt ====
// R11-proven body: BOTH operands via global_load_lds (XOR-swizzled); grid
// bx = M-tile (fastest; B-panel stays L2-hot), by = N-tile. OUTMODE: 0
// normal (+bias/relu); 3 = fused x-projection epilogue.
template<int BIASMODE, int RELU, int OUTMODE>
__global__ __launch_bounds__(512, 2) void gemm3_k(
    const ushort* __restrict__ A, const ushort* __restrict__ B,
    ushort* __restrict__ C, const float* __restrict__ bias, int biasMask,
    int N, int K, int lda, int ldb, int ldc,
    long sAq, long sBq, long sCq,
    const ushort* __restrict__ Wc, const float* __restrict__ bcp)
{
  __shared__ __align__(16) ushort As[2 * 256 * 64];   // 64 KiB
  __shared__ __align__(16) ushort Bs[2 * 256 * 64];   // 64 KiB
  const int tid = threadIdx.x, lane = tid & 63, wv = tid >> 6;
  const int wm = wv >> 2, wn = wv & 3;                // 2M x 4N
  const long bm = (long)blockIdx.x * 256, bn = (long)blockIdx.y * 256;
  const int z = blockIdx.z;
  const ushort* Ap = A + (long)z * sAq + bm * lda;
  const ushort* Bp = B + (long)z * sBq + bn * ldb;
  ushort* Cp = C + (long)z * sCq;
  const int nt = K >> 6;

  const int srow = wv * 32 + (lane >> 3);
  const int scol = ((lane & 7) ^ (srow & 7)) << 3;    // XOR-pre-swizzled source
  const ushort* apb = Ap + (long)srow * lda + scol;
  const ushort* bpb = Bp + (long)srow * ldb + scol;

  #define STAGE3(T, D) { \
    const ushort* ap_ = apb + (T) * 64; \
    const ushort* bp_ = bpb + (T) * 64; \
    ushort* la_ = &As[(D) * 16384 + (wv * 32) * 64]; \
    ushort* lb_ = &Bs[(D) * 16384 + (wv * 32) * 64]; \
    _Pragma("unroll") \
    for (int i_ = 0; i_ < 4; ++i_) gl16(ap_ + (long)(i_ * 8) * lda, la_ + i_ * 512); \
    _Pragma("unroll") \
    for (int i_ = 0; i_ < 4; ++i_) gl16(bp_ + (long)(i_ * 8) * ldb, lb_ + i_ * 512); \
  }

  STAGE3(0, 0);
  if (nt > 1) { STAGE3(1, 1); WAIT_VM(8); }
  else        { WAIT_VM(0); }
  RAWBAR;

  f4 acc[8][4] = {};
  for (int t = 0; t < nt; ++t) {
    const int d = t & 1;
    const ushort* as = As + d * 16384;
    const ushort* bs = Bs + d * 16384;
    // ---- ks = 0 half ----
    bf8 b0[4], a0[8];
    #pragma unroll
    for (int n = 0; n < 4; ++n) {
      int r = wn * 64 + n * 16 + (lane & 15);
      b0[n] = *(const bf8*)(bs + r * 64 + (((lane >> 4) ^ (r & 7)) << 3));
    }
    #pragma unroll
    for (int m = 0; m < 8; ++m) {
      int r = wm * 128 + m * 16 + (lane & 15);
      a0[m] = *(const bf8*)(as + r * 64 + (((lane >> 4) ^ (r & 7)) << 3));
    }
    __builtin_amdgcn_s_setprio(1);
    #pragma unroll
    for (int m = 0; m < 8; ++m)
      #pragma unroll
      for (int n = 0; n < 4; ++n)
        acc[m][n] = __builtin_amdgcn_mfma_f32_16x16x32_bf16(a0[m], b0[n], acc[m][n], 0, 0, 0);
    __builtin_amdgcn_s_setprio(0);
    // ---- ks = 1 half ----
    bf8 b1[4], a1[8];
    #pragma unroll
    for (int n = 0; n < 4; ++n) {
      int r = wn * 64 + n * 16 + (lane & 15);
      b1[n] = *(const bf8*)(bs + r * 64 + (((4 + (lane >> 4)) ^ (r & 7)) << 3));
    }
    #pragma unroll
    for (int m = 0; m < 8; ++m) {
      int r = wm * 128 + m * 16 + (lane & 15);
      a1[m] = *(const bf8*)(as + r * 64 + (((4 + (lane >> 4)) ^ (r & 7)) << 3));
    }
    WAIT_LGKM0;          // all my reads of buf d landed in regs
    RAWBAR;              // every wave done reading buf d -> safe to overwrite
    if (t + 2 < nt) STAGE3(t + 2, d);
    __builtin_amdgcn_s_setprio(1);
    #pragma unroll
    for (int m = 0; m < 8; ++m)
      #pragma unroll
      for (int n = 0; n < 4; ++n)
        acc[m][n] = __builtin_amdgcn_mfma_f32_16x16x32_bf16(a1[m], b1[n], acc[m][n], 0, 0, 0);
    __builtin_amdgcn_s_setprio(0);
    if (t + 1 < nt) {
      if (t + 2 < nt) { WAIT_VM(8); }   // tile t+1 landed; t+2 stays in flight
      else            { WAIT_VM(0); }
      RAWBAR;
    }
  }
  #undef STAGE3

  if (OUTMODE == 3) {
    // --- stage P into LDS [s][h] (swizzled); t_local = wm: t0->As, t1->Bs ---
    ushort* Ps = (wm == 0) ? (ushort*)As : (ushort*)Bs;
    #pragma unroll
    for (int m = 0; m < 8; ++m) {
      int hq = m * 16 + ((lane >> 4) << 2);
      #pragma unroll
      for (int n = 0; n < 4; ++n) {
        int s = wn * 64 + n * 16 + (lane & 15);
        int key = (s & 7) << 4;
        #pragma unroll
        for (int rr = 0; rr < 4; ++rr)
          Ps[s * 128 + ((hq + rr) ^ key)] = f2b(acc[m][n][rr]);
      }
    }
    WAIT_LGKM0;   // drain my ds_writes before the raw barrier
    RAWBAR;
    // --- mini-GEMM: x[s,d] = sum_h P[s][h] * Wc[d][h] + bcp[d] ---
    const int tl = wm, sq = wn;
    const ushort* Pw = (tl == 0) ? (const ushort*)As : (const ushort*)Bs;
    const int sbase = sq * 64;
    f4 xacc[4][4] = {};
    #pragma unroll
    for (int kk = 0; kk < 4; ++kk) {
      bf8 pa[4], wb[4];
      int hq = kk * 32 + ((lane >> 4) << 3);
      #pragma unroll
      for (int mt = 0; mt < 4; ++mt) {
        int s = sbase + mt * 16 + (lane & 15);
        pa[mt] = *(const bf8*)(Pw + s * 128 + (hq ^ ((s & 7) << 4)));
      }
      #pragma unroll
      for (int ntt = 0; ntt < 4; ++ntt) {
        int dd = ntt * 16 + (lane & 15);
        wb[ntt] = *(const bf8*)(Wc + dd * 128 + hq);
      }
      #pragma unroll
      for (int mt = 0; mt < 4; ++mt)
        #pragma unroll
        for (int ntt = 0; ntt < 4; ++ntt)
          xacc[mt][ntt] = __builtin_amdgcn_mfma_f32_16x16x32_bf16(pa[mt], wb[ntt], xacc[mt][ntt], 0, 0, 0);
    }
    const int tg = (int)(bm >> 7) + tl;
    #pragma unroll
    for (int mt = 0; mt < 4; ++mt)
      #pragma unroll
      for (int ntt = 0; ntt < 4; ++ntt) {
        int dd = ntt * 16 + (lane & 15);
        float bb = bcp[dd];
        #pragma unroll
        for (int rr = 0; rr < 4; ++rr) {
          int s = sbase + mt * 16 + ((lane >> 4) << 2) + rr;
          long seq = (long)z * 1024 + bn + s;
          C[((long)tg * 8192 + seq) * 64 + dd] = f2b(xacc[mt][ntt][rr] + bb);
        }
      }
  } else {
    #pragma unroll
    for (int m = 0; m < 8; ++m) {
      int grow = (int)bm + wm * 128 + m * 16 + ((lane >> 4) << 2);
      #pragma unroll
      for (int n = 0; n < 4; ++n) {
        int col = (int)bn + wn * 64 + n * 16 + (lane & 15);
        #pragma unroll
        for (int rr = 0; rr < 4; ++rr) {
          float v = acc[m][n][rr];
          if (BIASMODE == 1) v += bias[col & biasMask];
          if (BIASMODE == 2) v += bias[(grow + rr) & biasMask];
          if (RELU) v = fmaxf(v, 0.f);
          Cp[(long)(grow + rr) * ldc + col] = f2b(v);
        }
      }
    }
  }
}

// ---------------- 128x128 bf16 MFMA GEMM, 2-phase dbuf ----------------------
// BSRC: 0 = B bf16 via global_load_lds; 1 = B f32 reg-staged + converted
// (ONLY valid when nt == 1, e.g. the K=64 XT gemm — counted vmcnt unused).
template<int BIASMODE, int RELU, int OUTMODE, int BSRC>
__global__ __launch_bounds__(256) void gemm2_k(
    const ushort* __restrict__ A, const void* __restrict__ Bv,
    ushort* __restrict__ C, const float* __restrict__ bias, int biasMask,
    int N, int K, int lda, int ldb, int ldc, int ZD,
    long sAq, long sAr, long sBq, long sBr, long sCq, long sCr)
{
  __shared__ __align__(16) ushort As[2 * 128 * 64];
  __shared__ __align__(16) ushort Bs[2 * 128 * 64];
  const int tid = threadIdx.x, lane = tid & 63, wv = tid >> 6;
  const int wm = wv >> 1, wn = wv & 1;
  int bx = blockIdx.x, by = blockIdx.y;
  const long bm = (long)bx * 128, bn = (long)by * 128;
  int z = blockIdx.z, zq = z, zr = 0;
  if (ZD > 1) { zq = z / ZD; zr = z - zq * ZD; }
  const ushort* Ap = A + (long)zq * sAq + (long)zr * sAr + bm * lda;
  ushort* Cp = C + (long)zq * sCq + (long)zr * sCr;
  const int nt = K >> 6;

  const int srow = wv * 32 + (lane >> 3);
  const int scol = ((lane & 7) ^ (srow & 7)) << 3;
  const ushort* apb = Ap + (long)srow * lda + scol;

  if (BSRC == 1) {
    // ---- nt==1 path: stage A via gl16; B from f32 via reg-convert ----
    const float* Bf = (const float*)Bv + (long)zq * sBq + (long)zr * sBr + bn * ldb;
    #pragma unroll
    for (int i_ = 0; i_ < 4; ++i_)
      gl16(apb + (long)(i_ * 8) * lda, &As[(wv * 32) * 64] + i_ * 512);
    #pragma unroll
    for (int i = 0; i < 4; ++i) {
      int row = (tid >> 3) + 32 * i;
      int b8 = tid & 7;
      ushort u[8];
      if (bn + row < N) {
        const float* p = Bf + (long)row * ldb + b8 * 8;
        f4 v0 = *(const f4*)p, v1 = *(const f4*)(p + 4);
        u[0] = f2b(v0[0]); u[1] = f2b(v0[1]); u[2] = f2b(v0[2]); u[3] = f2b(v0[3]);
        u[4] = f2b(v1[0]); u[5] = f2b(v1[1]); u[6] = f2b(v1[2]); u[7] = f2b(v1[3]);
      } else {
        #pragma unroll
        for (int j = 0; j < 8; ++j) u[j] = 0;
      }
      *(int4*)(&Bs[row * 64 + ((b8 ^ (row & 7)) << 3)]) = *(int4*)u;
    }
    WAIT_VM(0);
    WAIT_LGKM0;
    RAWBAR;
  } else {
    const ushort* Bp = (const ushort*)Bv + (long)zq * sBq + (long)zr * sBr + bn * ldb;
    const ushort* bpb = Bp + (long)srow * ldb + scol;
    #define STAGE(T, D) { \
      const ushort* ap_ = apb + (T) * 64; \
      const ushort* bp_ = bpb + (T) * 64; \
      ushort* la_ = &As[((D) * 128 + wv * 32) * 64]; \
      ushort* lb_ = &Bs[((D) * 128 + wv * 32) * 64]; \
      _Pragma("unroll") \
      for (int i_ = 0; i_ < 4; ++i_) gl16(ap_ + (long)(i_ * 8) * lda, la_ + i_ * 512); \
      _Pragma("unroll") \
      for (int i_ = 0; i_ < 4; ++i_) gl16(bp_ + (long)(i_ * 8) * ldb, lb_ + i_ * 512); \
    }
    STAGE(0, 0);
    if (nt > 1) { STAGE(1, 1); WAIT_VM(8); }
    else        { WAIT_VM(0); }
    RAWBAR;
    f4 acc[4][4] = {};
    for (int t = 0; t < nt; ++t) {
      const int d = t & 1;
      const ushort* as = As + d * 8192;
      const ushort* bs = Bs + d * 8192;
      bf8 af[4][2], bfv[4][2];
      #pragma unroll
      for (int mi = 0; mi < 4; ++mi) {
        int r = wm * 64 + mi * 16 + (lane & 15);
        #pragma unroll
        for (int kk = 0; kk < 2; ++kk) {
          int blk = kk * 4 + (lane >> 4);
          af[mi][kk] = *(const bf8*)(as + r * 64 + ((blk ^ (r & 7)) << 3));
        }
      }
      #pragma unroll
      for (int ni = 0; ni < 4; ++ni) {
        int r = wn * 64 + ni * 16 + (lane & 15);
        #pragma unroll
        for (int kk = 0; kk < 2; ++kk) {
          int blk = kk * 4 + (lane >> 4);
          bfv[ni][kk] = *(const bf8*)(bs + r * 64 + ((blk ^ (r & 7)) << 3));
        }
      }
      WAIT_LGKM0;
      RAWBAR;
      if (t + 2 < nt) STAGE(t + 2, d);
      #pragma unroll
      for (int kk = 0; kk < 2; ++kk)
        #pragma unroll
        for (int mi = 0; mi < 4; ++mi)
          #pragma unroll
          for (int ni = 0; ni < 4; ++ni)
            acc[mi][ni] = __builtin_amdgcn_mfma_f32_16x16x32_bf16(af[mi][kk], bfv[ni][kk], acc[mi][ni], 0, 0, 0);
      if (t + 1 < nt) {
        if (t + 2 < nt) { WAIT_VM(8); }
        else            { WAIT_VM(0); }
        RAWBAR;
      }
    }
    #undef STAGE
    #pragma unroll
    for (int mi = 0; mi < 4; ++mi)
      #pragma unroll
      for (int ni = 0; ni < 4; ++ni) {
        int col = (int)bn + wn * 64 + ni * 16 + (lane & 15);
        if (col < N) {
          #pragma unroll
          for (int rr = 0; rr < 4; ++rr) {
            int row = (int)bm + wm * 64 + mi * 16 + (lane >> 4) * 4 + rr;
            float v = acc[mi][ni][rr];
            if (BIASMODE == 1) v += bias[col & biasMask];
            if (BIASMODE == 2) v += bias[row & biasMask];
            if (RELU) v = fmaxf(v, 0.f);
            Cp[(long)row * ldc + col] = f2b(v);
          }
        }
      }
    return;
  }

  // ---- BSRC==1 compute (single K-tile) ----
  f4 acc[4][4] = {};
  {
    const ushort* as = As;
    const ushort* bs = Bs;
    bf8 af[4][2], bfv[4][2];
    #pragma unroll
    for (int mi = 0; mi < 4; ++mi) {
      int r = wm * 64 + mi * 16 + (lane & 15);
      #pragma unroll
      for (int kk = 0; kk < 2; ++kk) {
        int blk = kk * 4 + (lane >> 4);
        af[mi][kk] = *(const bf8*)(as + r * 64 + ((blk ^ (r & 7)) << 3));
      }
    }
    #pragma unroll
    for (int ni = 0; ni < 4; ++ni) {
      int r = wn * 64 + ni * 16 + (lane & 15);
      #pragma unroll
      for (int kk = 0; kk < 2; ++kk) {
        int blk = kk * 4 + (lane >> 4);
        bfv[ni][kk] = *(const bf8*)(bs + r * 64 + ((blk ^ (r & 7)) << 3));
      }
    }
    WAIT_LGKM0;
    #pragma unroll
    for (int kk = 0; kk < 2; ++kk)
      #pragma unroll
      for (int mi = 0; mi < 4; ++mi)
        #pragma unroll
        for (int ni = 0; ni < 4; ++ni)
          acc[mi][ni] = __builtin_amdgcn_mfma_f32_16x16x32_bf16(af[mi][kk], bfv[ni][kk], acc[mi][ni], 0, 0, 0);
  }
  #pragma unroll
  for (int mi = 0; mi < 4; ++mi)
    #pragma unroll
    for (int ni = 0; ni < 4; ++ni) {
      int col = (int)bn + wn * 64 + ni * 16 + (lane & 15);
      if (col < N) {
        #pragma unroll
        for (int rr = 0; rr < 4; ++rr) {
          int row = (int)bm + wm * 64 + mi * 16 + (lane >> 4) * 4 + rr;
          float v = acc[mi][ni][rr];
          if (BIASMODE == 1) v += bias[col & biasMask];
          if (BIASMODE == 2) v += bias[row & biasMask];
          if (RELU) v = fmaxf(v, 0.f);
          Cp[(long)row * ldc + col] = f2b(v);
        }
      }
    }
}

// ------------- split-K thin GEMM: M=128 tiles, bf16 partial output ---------
__global__ __launch_bounds__(256) void gemmsk_k(
    const ushort* __restrict__ A, const ushort* __restrict__ B,
    ushort* __restrict__ P, int Kc, int lda, int ldb,
    long sAq, long sBq)
{
  __shared__ __align__(16) ushort As[2 * 128 * 64];
  __shared__ __align__(16) ushort Bs[2 * 128 * 64];
  const int tid = threadIdx.x, lane = tid & 63, wv = tid >> 6;
  const int wm = wv >> 1, wn = wv & 1;
  const long bm = (long)blockIdx.x * 128, bn = (long)blockIdx.y * 128;
  const int kc = blockIdx.z & 3, zq = blockIdx.z >> 2;
  const ushort* Ap = A + (long)zq * sAq + kc * Kc + bm * lda;
  const ushort* Bp = B + (long)zq * sBq + kc * Kc + bn * ldb;
  const int nt = Kc >> 6;

  const int srow = wv * 32 + (lane >> 3);
  const int scol = ((lane & 7) ^ (srow & 7)) << 3;
  const ushort* apb = Ap + (long)srow * lda + scol;
  const ushort* bpb = Bp + (long)srow * ldb + scol;

  #define STAGEK(T, D) { \
    const ushort* ap_ = apb + (T) * 64; \
    const ushort* bp_ = bpb + (T) * 64; \
    ushort* la_ = &As[((D) * 128 + wv * 32) * 64]; \
    ushort* lb_ = &Bs[((D) * 128 + wv * 32) * 64]; \
    _Pragma("unroll") \
    for (int i_ = 0; i_ < 4; ++i_) gl16(ap_ + (long)(i_ * 8) * lda, la_ + i_ * 512); \
    _Pragma("unroll") \
    for (int i_ = 0; i_ < 4; ++i_) gl16(bp_ + (long)(i_ * 8) * ldb, lb_ + i_ * 512); \
  }

  STAGEK(0, 0);
  if (nt > 1) { STAGEK(1, 1); WAIT_VM(8); }
  else        { WAIT_VM(0); }
  RAWBAR;

  f4 acc[4][4] = {};
  for (int t = 0; t < nt; ++t) {
    const int d = t & 1;
    const ushort* as = As + d * 8192;
    const ushort* bs = Bs + d * 8192;
    bf8 af[4][2], bfv[4][2];
    #pragma unroll
    for (int mi = 0; mi < 4; ++mi) {
      int r = wm * 64 + mi * 16 + (lane & 15);
      #pragma unroll
      for (int kk = 0; kk < 2; ++kk) {
        int blk = kk * 4 + (lane >> 4);
        af[mi][kk] = *(const bf8*)(as + r * 64 + ((blk ^ (r & 7)) << 3));
      }
    }
    #pragma unroll
    for (int ni = 0; ni < 4; ++ni) {
      int r = wn * 64 + ni * 16 + (lane & 15);
      #pragma unroll
      for (int kk = 0; kk < 2; ++kk) {
        int blk = kk * 4 + (lane >> 4);
        bfv[ni][kk] = *(const bf8*)(bs + r * 64 + ((blk ^ (r & 7)) << 3));
      }
    }
    WAIT_LGKM0;
    RAWBAR;
    if (t + 2 < nt) STAGEK(t + 2, d);
    #pragma unroll
    for (int kk = 0; kk < 2; ++kk)
      #pragma unroll
      for (int mi = 0; mi < 4; ++mi)
        #pragma unroll
        for (int ni = 0; ni < 4; ++ni)
          acc[mi][ni] = __builtin_amdgcn_mfma_f32_16x16x32_bf16(af[mi][kk], bfv[ni][kk], acc[mi][ni], 0, 0, 0);
    if (t + 1 < nt) {
      if (t + 2 < nt) { WAIT_VM(8); }
      else            { WAIT_VM(0); }
      RAWBAR;
    }
  }
  #undef STAGEK

  ushort* Pp = P + (long)blockIdx.z * 131072;
  #pragma unroll
  for (int mi = 0; mi < 4; ++mi)
    #pragma unroll
    for (int ni = 0; ni < 4; ++ni) {
      int col = (int)bn + wn * 64 + ni * 16 + (lane & 15);
      #pragma unroll
      for (int rr = 0; rr < 4; ++rr) {
        int row = (int)bm + wm * 64 + mi * 16 + (lane >> 4) * 4 + rr;
        Pp[(long)row * 1024 + col] = f2b(acc[mi][ni][rr]);
      }
    }
}

// ------------- split-K reduce: sum 4 bf16 partial slabs -> bf16 -------------
template<int RELU>
__global__ __launch_bounds__(256) void redk_k(const ushort* __restrict__ P,
                                              ushort* __restrict__ C) {
  int idx = blockIdx.x * 256 + threadIdx.x;   // 262144 (8z x 32768 groups of 4)
  long z = idx >> 15;
  long rem = (long)(idx & 32767) * 4;
  const ushort* base = P + z * 4 * 131072 + rem;
  float s[4] = {0.f, 0.f, 0.f, 0.f};
  #pragma unroll
  for (int kc = 0; kc < 4; ++kc) {
    ushort4 v = *(const ushort4*)(base + kc * 131072);
    s[0] += b2f(v.x); s[1] += b2f(v.y); s[2] += b2f(v.z); s[3] += b2f(v.w);
  }
  ushort4 o;
  #pragma unroll
  for (int j = 0; j < 4; ++j) {
    float v = s[j];
    if (RELU) v = fmaxf(v, 0.f);
    ((ushort*)&o)[j] = f2b(v);
  }
  *(ushort4*)(C + z * 131072 + rem) = o;
}

// ---------------- fused 2-layer GRU, register-carried h ----------------
__global__ __launch_bounds__(256, 2) void gru_k(
    const ushort* __restrict__ xT,   // (32, 8192, 64)
    const float* __restrict__ Wx0, const float* __restrict__ Wh0,
    const float* __restrict__ bx0, const float* __restrict__ bh0,
    const float* __restrict__ Wx1, const float* __restrict__ Wh1,
    const float* __restrict__ bx1, const float* __restrict__ bh1,
    ushort* __restrict__ rout)       // (8192, 32, 64)
{
  __shared__ ushort hbf[2][2][1024];   // [layer][buf][16*64], XOR-swizzled
  const int tid = threadIdx.x, lane = tid & 63, w = tid >> 6;
  const int seq0 = blockIdx.x * 16;
  for (int i = tid; i < 4096; i += 256) ((ushort*)hbf)[i] = 0;

  const float* Wxp[2] = {Wx0, Wx1};
  const float* Whp[2] = {Wh0, Wh1};
  const float* bxp[2] = {bx0, bx1};
  const float* bhp[2] = {bh0, bh1};
  bf8 Wxf[2][3][2], Whf[2][3][2];
  float bxv[2][3], bhv[2][3];
  #pragma unroll
  for (int L = 0; L < 2; ++L)
    #pragma unroll
    for (int g = 0; g < 3; ++g) {
      int row = g * 64 + w * 16 + (lane & 15);
      bxv[L][g] = bxp[L][row];
      bhv[L][g] = bhp[L][row];
      #pragma unroll
      for (int kk = 0; kk < 2; ++kk) {
        int kb = kk * 32 + (lane >> 4) * 8;
        Wxf[L][g][kk] = pack8(Wxp[L] + row * 64 + kb);
        Whf[L][g][kk] = pack8(Whp[L] + row * 64 + kb);
      }
    }
  __syncthreads();

  const int arow = lane & 15;
  const int col = w * 16 + (lane & 15);
  f4 hprev[2] = {{0.f,0.f,0.f,0.f},{0.f,0.f,0.f,0.f}};
  int pv = 0;
  for (int t = 0; t < 32; ++t) {
    const int cur = pv ^ 1;
    #pragma unroll
    for (int L = 0; L < 2; ++L) {
      bf8 axf[2], ahf[2];
      if (L == 0) {
        const ushort* xb = xT + ((long)t * 8192 + seq0 + arow) * 64 + (lane >> 4) * 8;
        axf[0] = *(const bf8*)(xb);
        axf[1] = *(const bf8*)(xb + 32);
      } else {
        #pragma unroll
        for (int kk = 0; kk < 2; ++kk) {
          int blk = kk * 4 + (lane >> 4);
          axf[kk] = *(const bf8*)(&hbf[0][cur][arow * 64 + ((blk ^ (arow & 7)) << 3)]);
        }
      }
      #pragma unroll
      for (int kk = 0; kk < 2; ++kk) {
        int blk = kk * 4 + (lane >> 4);
        ahf[kk] = *(const bf8*)(&hbf[L][pv][arow * 64 + ((blk ^ (arow & 7)) << 3)]);
      }
      f4 aX[3] = {}; f4 aH[3] = {};
      #pragma unroll
      for (int kk = 0; kk < 2; ++kk)
        #pragma unroll
        for (int g = 0; g < 3; ++g) {
          aX[g] = __builtin_amdgcn_mfma_f32_16x16x32_bf16(axf[kk], Wxf[L][g][kk], aX[g], 0, 0, 0);
          aH[g] = __builtin_amdgcn_mfma_f32_16x16x32_bf16(ahf[kk], Whf[L][g][kk], aH[g], 0, 0, 0);
        }
      f4 hn;
      #pragma unroll
      for (int r = 0; r < 4; ++r) {
        float rg = sigm(aX[0][r] + bxv[L][0] + aH[0][r] + bhv[L][0]);
        float zg = sigm(aX[1][r] + bxv[L][1] + aH[1][r] + bhv[L][1]);
        float cand = tanh_f(aX[2][r] + bxv[L][2] + rg * (aH[2][r] + bhv[L][2]));
        hn[r] = (1.f - zg) * cand + zg * hprev[L][r];
      }
      hprev[L] = hn;
      #pragma unroll
      for (int r = 0; r < 4; ++r) {
        int row = (lane >> 4) * 4 + r;
        ushort hb = f2b(hn[r]);
        hbf[L][cur][row * 64 + (((col >> 3) ^ (row & 7)) << 3) + (col & 7)] = hb;
        if (L == 1) rout[((long)(seq0 + row) * 32 + t) * 64 + col] = hb;
      }
      __syncthreads();
    }
    pv = cur;
  }
}

// ------------- fused temporal attention + residual + LayerNorm -------------
__global__ __launch_bounds__(256) void attn_k(
    const ushort* __restrict__ r,
    const float* __restrict__ Wq, const float* __restrict__ Wk,
    const float* __restrict__ Wv, const float* __restrict__ Wo,
    const float* __restrict__ lng, const float* __restrict__ lnb,
    ushort* __restrict__ enc)
{
  __shared__ ushort q_s[4][32][40];
  __shared__ ushort k_s[4][32][40];
  __shared__ ushort v_s[4][16][40];
  __shared__ ushort p_s[4][32][40];
  __shared__ ushort o_s[32][88];
  __shared__ float  ln_s[32][68];
  const int tid = threadIdx.x, lane = tid & 63, w = tid >> 6;
  const long n = blockIdx.x;

  for (int i = tid; i < 4 * 32 * 40; i += 256) { ((ushort*)q_s)[i] = 0; ((ushort*)k_s)[i] = 0; }

  bf8 wqf[2], wkf[2], wvf[2], wof[2];
  #pragma unroll
  for (int kk = 0; kk < 2; ++kk) {
    int row = w * 16 + (lane & 15);
    int kb = kk * 32 + (lane >> 4) * 8;
    wqf[kk] = pack8(Wq + row * 64 + kb);
    wkf[kk] = pack8(Wk + row * 64 + kb);
    wvf[kk] = pack8(Wv + row * 64 + kb);
    wof[kk] = pack8(Wo + row * 64 + kb);
  }
  __syncthreads();

  bf8 ar[2][2];
  #pragma unroll
  for (int mi = 0; mi < 2; ++mi)
    #pragma unroll
    for (int kk = 0; kk < 2; ++kk)
      ar[mi][kk] = *(const bf8*)(r + (n * 32 + mi * 16 + (lane & 15)) * 64 + kk * 32 + (lane >> 4) * 8);
  f4 aq[2] = {}, ak[2] = {}, av[2] = {};
  #pragma unroll
  for (int kk = 0; kk < 2; ++kk)
    #pragma unroll
    for (int mi = 0; mi < 2; ++mi) {
      aq[mi] = __builtin_amdgcn_mfma_f32_16x16x32_bf16(ar[mi][kk], wqf[kk], aq[mi], 0, 0, 0);
      ak[mi] = __builtin_amdgcn_mfma_f32_16x16x32_bf16(ar[mi][kk], wkf[kk], ak[mi], 0, 0, 0);
      av[mi] = __builtin_amdgcn_mfma_f32_16x16x32_bf16(ar[mi][kk], wvf[kk], av[mi], 0, 0, 0);
    }
  #pragma unroll
  for (int mi = 0; mi < 2; ++mi)
    #pragma unroll
    for (int rr = 0; rr < 4; ++rr) {
      int row = mi * 16 + (lane >> 4) * 4 + rr;
      q_s[w][row][lane & 15] = f2b(aq[mi][rr]);
      k_s[w][row][lane & 15] = f2b(ak[mi][rr]);
      v_s[w][lane & 15][row] = f2b(av[mi][rr]);
    }

  bf8 a_q[2], b_k[2];
  #pragma unroll
  for (int mt = 0; mt < 2; ++mt)
    a_q[mt] = *(const bf8*)(&q_s[w][mt * 16 + (lane & 15)][(lane >> 4) * 8]);
  #pragma unroll
  for (int nt = 0; nt < 2; ++nt)
    b_k[nt] = *(const bf8*)(&k_s[w][nt * 16 + (lane & 15)][(lane >> 4) * 8]);
  f4 s_[2][2] = {};
  #pragma unroll
  for (int mt = 0; mt < 2; ++mt)
    #pragma unroll
    for (int nt = 0; nt < 2; ++nt)
      s_[mt][nt] = __builtin_amdgcn_mfma_f32_16x16x32_bf16(a_q[mt], b_k[nt], s_[mt][nt], 0, 0, 0);
  #pragma unroll
  for (int mt = 0; mt < 2; ++mt)
    #pragma unroll
    for (int rr = 0; rr < 4; ++rr) {
      int trow = mt * 16 + (lane >> 4) * 4 + rr;
      float s0 = s_[mt][0][rr] * 0.25f, s1 = s_[mt][1][rr] * 0.25f;
      int c0 = lane & 15, c1 = 16 + (lane & 15);
      if (c0 > trow) s0 = -1e30f;
      if (c1 > trow) s1 = -1e30f;
      float m = fmaxf(s0, s1);
      #pragma unroll
      for (int d = 1; d < 16; d <<= 1) m = fmaxf(m, __shfl_xor(m, d));
      float e0 = __expf(s0 - m), e1 = __expf(s1 - m);
      float sum = e0 + e1;
      #pragma unroll
      for (int d = 1; d < 16; d <<= 1) sum += __shfl_xor(sum, d);
      float inv = 1.f / sum;
      p_s[w][trow][c0] = f2b(e0 * inv);
      p_s[w][trow][c1] = f2b(e1 * inv);
    }

  bf8 b_v = *(const bf8*)(&v_s[w][lane & 15][(lane >> 4) * 8]);
  f4 o_[2] = {};
  #pragma unroll
  for (int mt = 0; mt < 2; ++mt) {
    bf8 a_p = *(const bf8*)(&p_s[w][mt * 16 + (lane & 15)][(lane >> 4) * 8]);
    o_[mt] = __builtin_amdgcn_mfma_f32_16x16x32_bf16(a_p, b_v, o_[mt], 0, 0, 0);
  }
  #pragma unroll
  for (int mt = 0; mt < 2; ++mt)
    #pragma unroll
    for (int rr = 0; rr < 4; ++rr)
      o_s[mt * 16 + (lane >> 4) * 4 + rr][w * 16 + (lane & 15)] = f2b(o_[mt][rr]);
  __syncthreads();

  bf8 a_o[2][2];
  #pragma unroll
  for (int mt = 0; mt < 2; ++mt)
    #pragma unroll
    for (int kk = 0; kk < 2; ++kk)
      a_o[mt][kk] = *(const bf8*)(&o_s[mt * 16 + (lane & 15)][kk * 32 + (lane >> 4) * 8]);
  f4 oo[2] = {};
  #pragma unroll
  for (int kk = 0; kk < 2; ++kk)
    #pragma unroll
    for (int mt = 0; mt < 2; ++mt)
      oo[mt] = __builtin_amdgcn_mfma_f32_16x16x32_bf16(a_o[mt][kk], wof[kk], oo[mt], 0, 0, 0);
  #pragma unroll
  for (int mt = 0; mt < 2; ++mt)
    #pragma unroll
    for (int rr = 0; rr < 4; ++rr) {
      int row = mt * 16 + (lane >> 4) * 4 + rr;
      int col = w * 16 + (lane & 15);
      float resid = b2f(r[(n * 32 + row) * 64 + col]);
      ln_s[row][col] = oo[mt][rr] + resid;
    }
  __syncthreads();

  {
    int row = tid >> 3, seg = tid & 7;
    float vals[8], sm = 0.f, sq = 0.f;
    #pragma unroll
    for (int j = 0; j < 8; ++j) {
      float v = ln_s[row][seg * 8 + j];
      vals[j] = v; sm += v; sq += v * v;
    }
    #pragma unroll
    for (int d = 1; d < 8; d <<= 1) { sm += __shfl_xor(sm, d); sq += __shfl_xor(sq, d); }
    float mu = sm * (1.f / 64.f);
    float var = sq * (1.f / 64.f) - mu * mu;
    float rs = rsqrtf(var + 1e-6f);
    union { ushort u[8]; int4 v; } ou;
    #pragma unroll
    for (int j = 0; j < 8; ++j) {
      int c = seg * 8 + j;
      ou.u[j] = f2b((vals[j] - mu) * rs * lng[c] + lnb[c]);
    }
    *(int4*)(enc + (n * 32 + row) * 64 + seg * 8) = ou.v;
  }
}

// ------------- final: out[(b,s),c] = sum_d hg3aT[b][d][s] * Wfin[d,c] -------
__global__ __launch_bounds__(256) void final2_k(const ushort* __restrict__ hg3aT,
                                                const float* __restrict__ wf,
                                                float* __restrict__ out) {
  int i = blockIdx.x * 256 + threadIdx.x;  // 8192
  int b = i >> 10, s = i & 1023;
  const ushort* base = hg3aT + (long)b * 131072 + s;
  float a0 = 0.f, a1 = 0.f;
  #pragma unroll
  for (int d = 0; d < 128; ++d) {
    float v = b2f(base[d * 1024]);
    a0 += v * wf[2 * d];
    a1 += v * wf[2 * d + 1];
  }
  out[2 * i] = a0; out[2 * i + 1] = a1;
}

extern "C" void kernel_launch(void* const* d_in, const int* in_sizes, int n_in,
                              void* d_out, int out_size, void* d_ws, size_t ws_size,
                              hipStream_t stream) {
  const float* src = (const float*)d_in[0];
  const float* H   = (const float*)d_in[1];
  const float* adj = (const float*)d_in[2];
  const float* gW1 = (const float*)d_in[4];
  const float* gb1 = (const float*)d_in[5];
  const float* gW2 = (const float*)d_in[6];
  const float* gb2 = (const float*)d_in[7];
  const float* Wm  = (const float*)d_in[8];
  const float* bm  = (const float*)d_in[9];
  const float* Wl  = (const float*)d_in[10];
  const float* bl  = (const float*)d_in[11];
  const float* Wx0 = (const float*)d_in[12];
  const float* Wh0 = (const float*)d_in[13];
  const float* bx0 = (const float*)d_in[14];
  const float* bh0 = (const float*)d_in[15];
  const float* Wx1 = (const float*)d_in[16];
  const float* Wh1 = (const float*)d_in[17];
  const float* bx1 = (const float*)d_in[18];
  const float* bh1 = (const float*)d_in[19];
  const float* Wq  = (const float*)d_in[20];
  const float* Wk  = (const float*)d_in[21];
  const float* Wv  = (const float*)d_in[22];
  const float* Wo  = (const float*)d_in[23];
  const float* lng = (const float*)d_in[24];
  const float* lnb = (const float*)d_in[25];
  const float* Wg1 = (const float*)d_in[26];
  const float* Wg2 = (const float*)d_in[27];
  const float* Wp  = (const float*)d_in[28];

  char* ws = (char*)d_ws;
  const size_t MB = 1048576ull;
  ushort* adj_bf  = (ushort*)(ws);                  // 0-2
  ushort* Hnew_bf = (ushort*)(ws + 2 * MB);         // 2-4
  ushort* H_bf    = (ushort*)(ws + 4 * MB);
  ushort* Wm_bf   = (ushort*)(ws + 4 * MB + 262144);
  ushort* W1T     = (ushort*)(ws + 4 * MB + 524288);
  ushort* WcT     = (ushort*)(ws + 4 * MB + 524288 + 16384);
  float*  bc      = (float*) (ws + 4 * MB + 524288 + 32768);
  float*  wfin    = (float*) (ws + 4 * MB + 524288 + 33792);
  ushort* Wg1T    = (ushort*)(ws + 5 * MB);         // 5-6
  ushort* adjcat  = (ushort*)(ws + 6 * MB);         // 6-10
  ushort* XT      = (ushort*)(ws + 38 * MB);        // 38-102 (dead after layer-1)
  ushort* xT      = (ushort*)(ws + 38 * MB);        // 38-70 over XT (layer-2 out)
  ushort* r_bf    = (ushort*)(ws + 70 * MB);        // 70-102
  ushort* h1cat   = (ushort*)(ws + 102 * MB);       // 102-230 (dead after layer-2)
  ushort* enc     = (ushort*)(ws + 102 * MB);       // 102-134 over h1cat head
  ushort* Pk      = (ushort*)(ws + 134 * MB);       // 134-142 (bf16 partials)
  ushort* g1T     = (ushort*)(ws + 150 * MB);       // 150-152
  ushort* hgT     = (ushort*)(ws + 152 * MB);       // 152-154
  ushort* hg3aT   = (ushort*)(ws + 154 * MB);       // 154-156

  auto CVT = [&](const float* in, ushort* out, int n) {
    int n4 = n >> 2;
    cvt_k<<<dim3((n4 + 255) / 256), dim3(256), 0, stream>>>(in, out, n4);
  };
  CVT(adj, adj_bf, 1048576);
  CVT(H, H_bf, 131072);
  CVT(Wm, Wm_bf, 131072);
  cvtT_k<<<dim3(1, 2), 256, 0, stream>>>(gW1, W1T, 64, 128);
  cvtT_k<<<dim3(32, 2), 256, 0, stream>>>(Wg1, Wg1T, 2048, 128);
  wcombT_k<<<dim3(32), 256, 0, stream>>>(Wl, gW2, WcT);
  biasc_k<<<dim3(1), 64, 0, stream>>>(gb2, Wl, bl, bc);
  wfin_k<<<dim3(1), 256, 0, stream>>>(Wg2, Wp, wfin);

  // H_new = H @ Wm^T + bm  (fills second half of the stacked B)
  gemm2_k<1,0,0,0><<<dim3(8,8,1),256,0,stream>>>(H_bf, Wm_bf, Hnew_bf, bm, 1023,
      1024, 128, 128, 128, 1024, 1, 0,0, 0,0, 0,0);
  // XT[b][t][h][s] = (src@W1)^T — B = f32 src, converted during staging (nt==1)
  gemm2_k<0,0,0,1><<<dim3(1,8,256),256,0,stream>>>(W1T, src, XT, nullptr, 0,
      1024, 64, 64, 2048, 1024, 32, 0,0, 2097152,64, 4194304,131072);
  // adjcat[s'] = [adj[s'] | Hnew[s']]
  cat_k<<<dim3(512),256,0,stream>>>(adj_bf, Hnew_bf, adjcat);
  // layer-1 props fused: h1cat = relu(XT @ [adj;Hnew]^T + b1)
  gemm3_k<2,1,0><<<dim3(16,8,8),512,0,stream>>>(XT, adj_bf, h1cat, gb1, 127,
      2048, 1024, 1024, 1024, 2048, 4194304, 0, 8388608, nullptr, nullptr);
  // layer-2 props fused (K=2048) + fused x-projection -> xT (t, seq, h)
  gemm3_k<0,0,3><<<dim3(16,4,8),512,0,stream>>>(h1cat, adjcat, xT, nullptr, 0,
      1024, 2048, 2048, 2048, 0, 8388608, 0, 0, WcT, bc);
  // 2-layer GRU (register-carried h)
  gru_k<<<dim3(512),dim3(256),0,stream>>>(xT, Wx0,Wh0,bx0,bh0, Wx1,Wh1,bx1,bh1, r_bf);
  // fused attention + residual + LN -> enc
  attn_k<<<dim3(8192),dim3(256),0,stream>>>(r_bf, Wq,Wk,Wv,Wo, lng,lnb, enc);
  // HGN via split-K x4 (256 blocks each, bf16 partials) + reduce
  gemmsk_k<<<dim3(1,8,32),256,0,stream>>>(Wg1T, enc, Pk, 512, 2048, 2048, 0, 2097152);
  redk_k<0><<<dim3(1024),256,0,stream>>>(Pk, g1T);
  gemmsk_k<<<dim3(1,8,32),256,0,stream>>>(g1T, adj_bf, Pk, 256, 1024, 1024, 131072, 0);
  redk_k<1><<<dim3(1024),256,0,stream>>>(Pk, hgT);
  gemmsk_k<<<dim3(1,8,32),256,0,stream>>>(hgT, adj_bf, Pk, 256, 1024, 1024, 131072, 0);
  redk_k<0><<<dim3(1024),256,0,stream>>>(Pk, hg3aT);
  final2_k<<<dim3(32),256,0,stream>>>(hg3aT, wfin, (float*)d_out);
}